// Round 8
// baseline (539.269 us; speedup 1.0000x reference)
//
#include <hip/hip_runtime.h>
#include <hip/hip_bf16.h>
#include <math.h>

#define NND 50000
#define NE 800000
#define NF 128
#define NH 64
#define NB 512
#define KP 30
#define NCLS 10
#define NBKT 49              // coarse buckets of 1024 dsts

typedef __hip_bfloat16 bf16;
typedef unsigned long long u64;

__device__ __forceinline__ float ldF(const void* p, size_t i, int isbf){
    return isbf ? __bfloat162float(((const bf16*)p)[i]) : ((const float*)p)[i];
}

// ---------------- dtype probe: flags[0]=floats-are-bf16, flags[1]=ints-are-int64 ----
__global__ void probe_kernel(const unsigned int* __restrict__ xw,
                             const int* __restrict__ ew, int* __restrict__ flags){
    __shared__ int cF, cI;
    if (threadIdx.x == 0){ cF = 0; cI = 0; }
    __syncthreads();
    unsigned int w = xw[threadIdx.x];
    int ex = (int)((w >> 7) & 0xFF);
    if (ex >= 100 && ex <= 140) atomicAdd(&cF, 1);
    if (ew[2*threadIdx.x + 1] == 0) atomicAdd(&cI, 1);
    __syncthreads();
    if (threadIdx.x == 0){
        flags[0] = (cF >= 128) ? 1 : 0;
        flags[1] = (cI >= 192) ? 1 : 0;
    }
}

__device__ __forceinline__ int edgeSrc(const int* ei, int e, int i64){
    return i64 ? ei[2*e] : ei[e];
}
__device__ __forceinline__ int edgeDst(const int* ei, int e, int i64){
    return i64 ? ei[2*NE + 2*e] : ei[NE + e];
}

// ------------- setup: starts + fp32 preconvert + layer-weight transpose ------
__global__ __launch_bounds__(256) void setup_kernel(
    const int* __restrict__ batch, int* __restrict__ starts,
    const void* W1l, const void* W1r, const void* b1,
    const void* W2l, const void* W2r, const void* b2,
    const void* W3l, const void* W3r, const void* b3,
    const void* convw, const void* convb,
    const void* l1w, const void* l1b, const void* l2w, const void* l2b,
    float* __restrict__ w1lT, float* __restrict__ w1rT, float* __restrict__ b1f,
    float* __restrict__ w2lT, float* __restrict__ w2rT, float* __restrict__ b2f,
    float* __restrict__ w3lT, float* __restrict__ w3rT, float* __restrict__ b3f,
    float* __restrict__ wT, float* __restrict__ cbf,
    float* __restrict__ l1wf, float* __restrict__ l1bf,
    float* __restrict__ l2wf, float* __restrict__ l2bf,
    const int* __restrict__ flags)
{
    int wbf = flags[0];
    int i64 = flags[1];
    int i = blockIdx.x*256 + threadIdx.x;
    if (i < NND){
        int b  = i64 ? batch[2*i] : batch[i];
        int pb = (i == 0) ? -1 : (i64 ? batch[2*(i-1)] : batch[i-1]);
        for (int g = pb+1; g <= b; ++g) starts[g] = i;
        if (i == NND-1) for (int g = b+1; g <= NB; ++g) starts[g] = NND;
    }
    if (i < 8192){               // W1: [128][64] -> [64][128]
        int k = i >> 6, f = i & 63;
        w1lT[f*NF + k] = ldF(W1l, i, wbf);
        w1rT[f*NF + k] = ldF(W1r, i, wbf);
    }
    if (i < 4096){               // W2/W3: [64][64] -> [64][64]
        int k = i >> 6, f = i & 63;
        w2lT[f*NH + k] = ldF(W2l, i, wbf);
        w2rT[f*NH + k] = ldF(W2r, i, wbf);
        w3lT[f*NH + k] = ldF(W3l, i, wbf);
        w3rT[f*NH + k] = ldF(W3r, i, wbf);
    }
    if (i < 64){
        b1f[i] = ldF(b1, i, wbf);
        b2f[i] = ldF(b2, i, wbf);
        b3f[i] = ldF(b3, i, wbf);
        l1bf[i] = ldF(l1b, i, wbf);
    }
    if (i < 10240){
        int o = i / 320, rem = i - o*320, ch = rem/5, h = rem - ch*5;
        wT[ch*160 + h*32 + o] = ldF(convw, i, wbf);   // wT[ch][h][o]
    }
    if (i < 53248) l1wf[i] = ldF(l1w, i, wbf);
    if (i < 640)   l2wf[i] = ldF(l2w, i, wbf);
    if (i < 32)    cbf[i]  = ldF(convb, i, wbf);
    if (i < 10)    l2bf[i] = ldF(l2b, i, wbf);
}

// ============ CSR build via 2-level bucket sort ============
__global__ __launch_bounds__(256) void bucket_count(const int* __restrict__ ei,
                                                    int* __restrict__ bcnt,
                                                    const int* __restrict__ flags){
    __shared__ int lh[NBKT];
    int tid = threadIdx.x;
    int i64 = flags[1];
    if (tid < NBKT) lh[tid] = 0;
    __syncthreads();
    int t0 = blockIdx.x*4096;
    #pragma unroll 4
    for (int k = 0; k < 16; ++k){
        int e = t0 + k*256 + tid;
        if (e < NE) atomicAdd(&lh[edgeDst(ei,e,i64) >> 10], 1);
    }
    __syncthreads();
    if (tid < NBKT && lh[tid]) atomicAdd(&bcnt[tid], lh[tid]);
}

__global__ void bucket_scan(const int* __restrict__ bcnt, int* __restrict__ bbase,
                            int* __restrict__ bcur, int* __restrict__ offs){
    if (threadIdx.x == 0){
        int acc = 0;
        for (int b = 0; b < NBKT; ++b){
            bbase[b] = acc; bcur[b] = acc; acc += bcnt[b];
        }
        bbase[NBKT] = acc;
        offs[NND] = NE;
    }
}

__global__ __launch_bounds__(256) void bucket_scatter(const int* __restrict__ ei,
                                                      int* __restrict__ bcur,
                                                      int2* __restrict__ bedges,
                                                      const int* __restrict__ flags){
    __shared__ int lh[NBKT];
    __shared__ int lcur[NBKT];
    int tid = threadIdx.x;
    int i64 = flags[1];
    if (tid < NBKT) lh[tid] = 0;
    __syncthreads();
    int t0 = blockIdx.x*4096;
    int myd[16], mys[16];
    int cnt = 0;
    #pragma unroll 4
    for (int k = 0; k < 16; ++k){
        int e = t0 + k*256 + tid;
        if (e < NE){
            int d = edgeDst(ei,e,i64), s_ = edgeSrc(ei,e,i64);
            myd[cnt] = d; mys[cnt] = s_; ++cnt;
            atomicAdd(&lh[d >> 10], 1);
        }
    }
    __syncthreads();
    if (tid < NBKT) lcur[tid] = lh[tid] ? atomicAdd(&bcur[tid], lh[tid]) : 0;
    __syncthreads();
    for (int k = 0; k < cnt; ++k){
        int b = myd[k] >> 10;
        int p = atomicAdd(&lcur[b], 1);
        bedges[p] = make_int2(mys[k], myd[k]);
    }
}

__global__ __launch_bounds__(1024) void csr_finalize(const int2* __restrict__ bedges,
                                                     const int* __restrict__ bbase,
                                                     int* __restrict__ offs,
                                                     int* __restrict__ csr){
    __shared__ int hist[1024];
    int b = blockIdx.x;
    int tid = threadIdx.x;
    int dst0 = b << 10;
    int nd = NND - dst0; if (nd > 1024) nd = 1024;
    int e0 = bbase[b], e1 = bbase[b+1];
    hist[tid] = 0;
    __syncthreads();
    for (int e = e0 + tid; e < e1; e += 1024)
        atomicAdd(&hist[bedges[e].y - dst0], 1);
    __syncthreads();
    int own = hist[tid];
    for (int st = 1; st < 1024; st <<= 1){
        int v = (tid >= st) ? hist[tid-st] : 0;
        __syncthreads();
        hist[tid] += v;
        __syncthreads();
    }
    int excl = hist[tid] - own;
    if (tid < nd) offs[dst0 + tid] = e0 + excl;
    __syncthreads();
    hist[tid] = excl;
    __syncthreads();
    for (int e = e0 + tid; e < e1; e += 1024){
        int2 ed = bedges[e];
        int p = atomicAdd(&hist[ed.y - dst0], 1);
        csr[e0 + p] = ed.x;
    }
}

// -------- dual GEMM v2: fp32 transposed weights, float4 loads, LDS-broadcast in ----
template<int K>
__global__ __launch_bounds__(256) void dualgemm2_kernel(
    const void* __restrict__ in, const float* __restrict__ WlT,
    const float* __restrict__ WrT, const float* __restrict__ bf,
    float* __restrict__ y, float* __restrict__ z,
    const int* __restrict__ flags, int inIsF32)
{
    __shared__ float inR[16*K];
    int isbf = inIsF32 ? 0 : flags[0];
    int tid = threadIdx.x;
    int base = blockIdx.x * 16;
    for (int i = tid; i < 16*K; i += 256){
        int r = i / K, c = i - r*K;
        int node = base + r;
        inR[i] = (node < NND) ? ldF(in, (size_t)node*K + c, isbf) : 0.f;
    }
    __syncthreads();
    int f = tid & 63, ng = tid >> 6;
    float ay[4] = {0,0,0,0}, az[4] = {0,0,0,0};
    const float4* wl4 = (const float4*)(WlT + f*K);
    const float4* wr4 = (const float4*)(WrT + f*K);
    const float4* r0 = (const float4*)(inR + (ng*4+0)*K);
    const float4* r1 = (const float4*)(inR + (ng*4+1)*K);
    const float4* r2 = (const float4*)(inR + (ng*4+2)*K);
    const float4* r3 = (const float4*)(inR + (ng*4+3)*K);
    #pragma unroll 4
    for (int k4 = 0; k4 < K/4; ++k4){
        float4 wl = wl4[k4], wr = wr4[k4];
        float4 v0 = r0[k4], v1 = r1[k4], v2 = r2[k4], v3 = r3[k4];
        ay[0] += wl.x*v0.x + wl.y*v0.y + wl.z*v0.z + wl.w*v0.w;
        ay[1] += wl.x*v1.x + wl.y*v1.y + wl.z*v1.z + wl.w*v1.w;
        ay[2] += wl.x*v2.x + wl.y*v2.y + wl.z*v2.z + wl.w*v2.w;
        ay[3] += wl.x*v3.x + wl.y*v3.y + wl.z*v3.z + wl.w*v3.w;
        az[0] += wr.x*v0.x + wr.y*v0.y + wr.z*v0.z + wr.w*v0.w;
        az[1] += wr.x*v1.x + wr.y*v1.y + wr.z*v1.z + wr.w*v1.w;
        az[2] += wr.x*v2.x + wr.y*v2.y + wr.z*v2.z + wr.w*v2.w;
        az[3] += wr.x*v3.x + wr.y*v3.y + wr.z*v3.z + wr.w*v3.w;
    }
    float bv = bf[f];
    #pragma unroll
    for (int j = 0; j < 4; ++j){
        int node = base + ng*4 + j;
        if (node < NND){
            y[(size_t)node*NH + f] = (j==0?ay[0]:j==1?ay[1]:j==2?ay[2]:ay[3]);
            z[(size_t)node*NH + f] = (j==0?az[0]:j==1?az[1]:j==2?az[2]:az[3]) + bv;
        }
    }
}

// -------- gather v2: 4 feature-chunk passes; per-pass y-slice (3.2MB) is L2-resident --
__global__ __launch_bounds__(256) void gather2_kernel(
    const float4* __restrict__ y4, const int* __restrict__ offs,
    const int* __restrict__ csr, const float4* __restrict__ z4,
    float4* __restrict__ out4)
{
    int t = blockIdx.x*256 + threadIdx.x;
    int node = t >> 2;
    if (node >= NND) return;
    int qq = (blockIdx.y << 2) | (t & 3);      // float4 index within 16-float4 row
    int o0 = offs[node], o1 = offs[node+1];
    float ax=0.f, ayv=0.f, azv=0.f, aw=0.f;
    int e = o0;
    for (; e + 3 < o1; e += 4){
        int s0 = csr[e], s1 = csr[e+1], s2 = csr[e+2], s3 = csr[e+3];
        float4 a = y4[(size_t)s0*16 + qq];
        float4 b = y4[(size_t)s1*16 + qq];
        float4 c = y4[(size_t)s2*16 + qq];
        float4 d = y4[(size_t)s3*16 + qq];
        ax  += a.x + b.x + c.x + d.x;
        ayv += a.y + b.y + c.y + d.y;
        azv += a.z + b.z + c.z + d.z;
        aw  += a.w + b.w + c.w + d.w;
    }
    for (; e < o1; ++e){
        float4 a = y4[(size_t)csr[e]*16 + qq];
        ax += a.x; ayv += a.y; azv += a.z; aw += a.w;
    }
    float dd = (float)(o1 - o0); dd = dd > 1.f ? dd : 1.f;
    float inv = 1.f / dd;
    float4 zz = z4[(size_t)node*16 + qq];
    float4 v;
    v.x = ax *inv + zz.x; v.y = ayv*inv + zz.y;
    v.z = azv*inv + zz.z; v.w = aw *inv + zz.w;
    v.x = v.x > 0.f ? v.x : 0.f;  v.y = v.y > 0.f ? v.y : 0.f;
    v.z = v.z > 0.f ? v.z : 0.f;  v.w = v.w > 0.f ? v.w : 0.f;
    out4[(size_t)node*16 + qq] = v;
}

// ------ head v3: bitonic-sort top-30 (all 256 threads) + conv + fc1 + fc2 + lsm ----
__global__ __launch_bounds__(256) void head3_kernel(
    const float* __restrict__ h3, const int* __restrict__ starts,
    const float* __restrict__ wT, const float* __restrict__ cbf,
    const float* __restrict__ l1wf, const float* __restrict__ l1bf,
    const float* __restrict__ l2wf, const float* __restrict__ l2bf,
    float* __restrict__ outp)
{
    __shared__ u64  keys[256];
    __shared__ int  sel[KP];
    __shared__ float pT[64*32];          // pT[ch][rank], ranks 30,31 zeroed
    __shared__ float part[8*832];
    __shared__ float cbuf[832];
    __shared__ float fbuf[NH];
    __shared__ float logitsS[NCLS];
    int g = blockIdx.x, tid = threadIdx.x;
    int s = starts[g], e = starts[g+1];
    int cnt = e - s; if (cnt > 256) cnt = 256; if (cnt < 0) cnt = 0;

    // key = (descending-order map of value) << 32 | index  -> ascending sort
    u64 key = 0xFFFFFFFFFFFFFFFFull;
    if (tid < cnt){
        float v = h3[(size_t)(s+tid)*NH + 63];
        unsigned u = __float_as_uint(v);
        unsigned m = (u & 0x80000000u) ? ~u : (u | 0x80000000u);  // ascending map
        unsigned d = ~m;                                          // descending
        key = ((u64)d << 32) | (unsigned)tid;
    }
    keys[tid] = key;
    __syncthreads();
    // bitonic sort, 256 elements, ascending
    for (int k = 2; k <= 256; k <<= 1){
        for (int j = k >> 1; j > 0; j >>= 1){
            int partner = tid ^ j;
            u64 a = keys[tid], b = keys[partner];
            bool up = ((tid & k) == 0);
            bool amin = a < b;
            u64 keep;
            if (partner > tid) keep = (up == amin) ? a : b;
            else               keep = (up == amin) ? b : a;
            __syncthreads();
            keys[tid] = keep;
            __syncthreads();
        }
    }
    if (tid < KP){
        u64 kk = keys[tid];
        sel[tid] = ((unsigned)(kk >> 32) == 0xFFFFFFFFu) ? -1 : (int)(kk & 0xFFFFFFFFu);
    }
    if (tid < 64){ pT[tid*32 + 30] = 0.f; pT[tid*32 + 31] = 0.f; }
    __syncthreads();
    // parallel coalesced gather of the 30 selected rows
    for (int i = tid; i < KP*64; i += 256){
        int r = i >> 6, f = i & 63;
        int li = sel[r];
        pT[f*32 + r] = (li >= 0) ? h3[(size_t)(s+li)*NH + f] : 0.f;
    }
    __syncthreads();

    int o = tid & 31, chg = tid >> 5;
    float acc[26];
    #pragma unroll
    for (int t = 0; t < 26; ++t) acc[t] = 0.f;
    for (int c8 = 0; c8 < 8; ++c8){
        int ch = chg*8 + c8;
        const float4* prow = (const float4*)&pT[ch*32];
        float p[32];
        #pragma unroll
        for (int q = 0; q < 8; ++q){
            float4 v = prow[q];
            p[4*q]=v.x; p[4*q+1]=v.y; p[4*q+2]=v.z; p[4*q+3]=v.w;
        }
        const float* wrow = &wT[ch*160 + o];
        #pragma unroll
        for (int h = 0; h < 5; ++h){
            float wv = wrow[h*32];
            #pragma unroll
            for (int t = 0; t < 26; ++t) acc[t] += p[t+h]*wv;
        }
    }
    #pragma unroll
    for (int t = 0; t < 26; ++t) part[chg*832 + o*26 + t] = acc[t];
    __syncthreads();

    for (int i = tid; i < 832; i += 256){
        int oo = i / 26;
        float a = cbf[oo];
        #pragma unroll
        for (int cg = 0; cg < 8; ++cg) a += part[cg*832 + i];
        cbuf[i] = a > 0.f ? a : 0.f;
    }
    __syncthreads();

    {   // fc1: 832 -> 64
        int p = tid >> 6, j = tid & 63;
        float a = 0.f;
        int m0 = p*208;
        #pragma unroll 4
        for (int m = m0; m < m0 + 208; ++m)
            a += cbuf[m] * l1wf[(size_t)m*NH + j];
        part[p*NH + j] = a;
    }
    __syncthreads();
    if (tid < NH){
        float v = part[tid] + part[NH+tid] + part[2*NH+tid] + part[3*NH+tid] + l1bf[tid];
        fbuf[tid] = v > 0.f ? v : 0.f;
    }
    __syncthreads();
    if (tid < NCLS){
        float a = l2bf[tid];
        #pragma unroll
        for (int j = 0; j < NH; ++j) a += fbuf[j] * l2wf[j*NCLS + tid];
        logitsS[tid] = a;
    }
    __syncthreads();
    if (tid == 0){
        float m = logitsS[0];
        for (int c = 1; c < NCLS; ++c) m = fmaxf(m, logitsS[c]);
        float ssum = 0.f;
        for (int c = 0; c < NCLS; ++c) ssum += expf(logitsS[c]-m);
        float lse = m + logf(ssum);
        for (int c = 0; c < NCLS; ++c)
            outp[(size_t)g*NCLS + c] = logitsS[c] - lse;
    }
}

extern "C" void kernel_launch(void* const* d_in, const int* in_sizes, int n_in,
                              void* d_out, int out_size, void* d_ws, size_t ws_size,
                              hipStream_t stream) {
    const void* x    = d_in[0];
    const int*  ei   = (const int*)d_in[1];
    const int*  batch= (const int*)d_in[2];
    const void *W1l=d_in[3], *b1=d_in[4],  *W1r=d_in[5];
    const void *W2l=d_in[6], *b2=d_in[7],  *W2r=d_in[8];
    const void *W3l=d_in[9], *b3=d_in[10], *W3r=d_in[11];
    const void *convw=d_in[12], *convb=d_in[13];
    const void *l1w=d_in[14], *l1b=d_in[15];
    const void *l2w=d_in[16], *l2b=d_in[17];
    float* out = (float*)d_out;

    float* wsf = (float*)d_ws;
    float* A  = wsf;                             // 50000*64
    float* Bb = A  + (size_t)NND*NH;             // 50000*64
    float* C  = Bb + (size_t)NND*NH;             // 50000*64
    int2* bedges = (int2*)(C + (size_t)NND*NH);  // 800000 int2
    float* w1lT = (float*)(bedges + NE);         // 8192
    float* w1rT = w1lT + 8192;                   // 8192
    float* w2lT = w1rT + 8192;                   // 4096
    float* w2rT = w2lT + 4096;                   // 4096
    float* w3lT = w2rT + 4096;                   // 4096
    float* w3rT = w3lT + 4096;                   // 4096
    float* b1f  = w3rT + 4096;                   // 64
    float* b2f  = b1f + 64;                      // 64
    float* b3f  = b2f + 64;                      // 64
    float* wT   = b3f + 64;                      // 10240
    float* cbf  = wT + 10240;                    // 32
    float* l1wf = cbf + 32;                      // 53248
    float* l1bf = l1wf + 53248;                  // 64
    float* l2wf = l1bf + 64;                     // 640
    float* l2bf = l2wf + 640;                    // 10 (+pad)
    int* starts = (int*)(l2bf + 16);             // 513
    int* flags  = starts + 520;                  // 2
    int* bcnt   = flags + 8;                     // 49
    int* bbase  = bcnt + 64;                     // 50
    int* bcur   = bbase + 64;                    // 49
    int* offs   = bcur + 64;                     // 50001
    int* csr    = offs + NND + 3;                // 800000

    probe_kernel<<<1, 256, 0, stream>>>((const unsigned int*)x, ei, flags);
    setup_kernel<<<(53248+255)/256, 256, 0, stream>>>(batch, starts,
        W1l, W1r, b1, W2l, W2r, b2, W3l, W3r, b3,
        convw, convb, l1w, l1b, l2w, l2b,
        w1lT, w1rT, b1f, w2lT, w2rT, b2f, w3lT, w3rT, b3f,
        wT, cbf, l1wf, l1bf, l2wf, l2bf, flags);

    // ---- CSR build via bucket sort ----
    const int NTILE = (NE + 4095)/4096;          // 196
    hipMemsetAsync(bcnt, 0, NBKT*sizeof(int), stream);
    bucket_count<<<NTILE, 256, 0, stream>>>(ei, bcnt, flags);
    bucket_scan<<<1, 64, 0, stream>>>(bcnt, bbase, bcur, offs);
    bucket_scatter<<<NTILE, 256, 0, stream>>>(ei, bcur, bedges, flags);
    csr_finalize<<<NBKT, 1024, 0, stream>>>(bedges, bbase, offs, csr);

    int gblocks = (NND + 15)/16;                 // 3125
    dim3 ggrid((NND*4 + 255)/256, 4);            // 782 x 4 chunks

    // ---- layer 1: x -> B ----
    dualgemm2_kernel<NF><<<gblocks,256,0,stream>>>(x, w1lT, w1rT, b1f, A, Bb, flags, 0);
    gather2_kernel<<<ggrid,256,0,stream>>>((const float4*)A, offs, csr, (const float4*)Bb, (float4*)Bb);

    // ---- layer 2: B -> C ----
    dualgemm2_kernel<NH><<<gblocks,256,0,stream>>>(Bb, w2lT, w2rT, b2f, A, C, flags, 1);
    gather2_kernel<<<ggrid,256,0,stream>>>((const float4*)A, offs, csr, (const float4*)C, (float4*)C);

    // ---- layer 3: C -> B ----
    dualgemm2_kernel<NH><<<gblocks,256,0,stream>>>(C, w3lT, w3rT, b3f, A, Bb, flags, 1);
    gather2_kernel<<<ggrid,256,0,stream>>>((const float4*)A, offs, csr, (const float4*)Bb, (float4*)Bb);

    // ---- head ----
    head3_kernel<<<NB,256,0,stream>>>(Bb, starts, wT, cbf, l1wf, l1bf, l2wf, l2bf, out);
}

// Round 9
// 425.644 us; speedup vs baseline: 1.2669x; 1.2669x over previous
//
#include <hip/hip_runtime.h>
#include <hip/hip_bf16.h>
#include <math.h>

#define NND 50000
#define NE 800000
#define NF 128
#define NH 64
#define NB 512
#define KP 30
#define NCLS 10
#define NBKT 49              // coarse buckets of 1024 dsts

typedef __hip_bfloat16 bf16;
typedef unsigned long long u64;

__device__ __forceinline__ float ldF(const void* p, size_t i, int isbf){
    return isbf ? __bfloat162float(((const bf16*)p)[i]) : ((const float*)p)[i];
}

// ---------------- dtype probe: flags[0]=floats-are-bf16, flags[1]=ints-are-int64 ----
__global__ void probe_kernel(const unsigned int* __restrict__ xw,
                             const int* __restrict__ ew, int* __restrict__ flags){
    __shared__ int cF, cI;
    if (threadIdx.x == 0){ cF = 0; cI = 0; }
    __syncthreads();
    unsigned int w = xw[threadIdx.x];
    int ex = (int)((w >> 7) & 0xFF);
    if (ex >= 100 && ex <= 140) atomicAdd(&cF, 1);
    if (ew[2*threadIdx.x + 1] == 0) atomicAdd(&cI, 1);
    __syncthreads();
    if (threadIdx.x == 0){
        flags[0] = (cF >= 128) ? 1 : 0;
        flags[1] = (cI >= 192) ? 1 : 0;
    }
}

__device__ __forceinline__ int edgeSrc(const int* ei, int e, int i64){
    return i64 ? ei[2*e] : ei[e];
}
__device__ __forceinline__ int edgeDst(const int* ei, int e, int i64){
    return i64 ? ei[2*NE + 2*e] : ei[NE + e];
}

// ------------- setup: starts + fp32 preconvert (weights keep [k][f] layout!) ------
// Lesson R8: [f][K] transpose gives per-thread contiguity but breaks inter-lane
// coalescing (64 lines/load). Keep [k][f]: lane=f -> one 256B segment per load.
__global__ __launch_bounds__(256) void setup_kernel(
    const int* __restrict__ batch, int* __restrict__ starts,
    const void* W1l, const void* W1r, const void* b1,
    const void* W2l, const void* W2r, const void* b2,
    const void* W3l, const void* W3r, const void* b3,
    const void* convw, const void* convb,
    const void* l1w, const void* l1b, const void* l2w, const void* l2b,
    float* __restrict__ w1lF, float* __restrict__ w1rF, float* __restrict__ b1f,
    float* __restrict__ w2lF, float* __restrict__ w2rF, float* __restrict__ b2f,
    float* __restrict__ w3lF, float* __restrict__ w3rF, float* __restrict__ b3f,
    float* __restrict__ wT, float* __restrict__ cbf,
    float* __restrict__ l1wf, float* __restrict__ l1bf,
    float* __restrict__ l2wf, float* __restrict__ l2bf,
    const int* __restrict__ flags)
{
    int wbf = flags[0];
    int i64 = flags[1];
    int i = blockIdx.x*256 + threadIdx.x;
    if (i < NND){
        int b  = i64 ? batch[2*i] : batch[i];
        int pb = (i == 0) ? -1 : (i64 ? batch[2*(i-1)] : batch[i-1]);
        for (int g = pb+1; g <= b; ++g) starts[g] = i;
        if (i == NND-1) for (int g = b+1; g <= NB; ++g) starts[g] = NND;
    }
    if (i < 8192){               // W1: [128][64] fp32 copy, same layout
        w1lF[i] = ldF(W1l, i, wbf);
        w1rF[i] = ldF(W1r, i, wbf);
    }
    if (i < 4096){               // W2/W3: [64][64]
        w2lF[i] = ldF(W2l, i, wbf);
        w2rF[i] = ldF(W2r, i, wbf);
        w3lF[i] = ldF(W3l, i, wbf);
        w3rF[i] = ldF(W3r, i, wbf);
    }
    if (i < 64){
        b1f[i] = ldF(b1, i, wbf);
        b2f[i] = ldF(b2, i, wbf);
        b3f[i] = ldF(b3, i, wbf);
        l1bf[i] = ldF(l1b, i, wbf);
    }
    if (i < 10240){
        int o = i / 320, rem = i - o*320, ch = rem/5, h = rem - ch*5;
        wT[ch*160 + h*32 + o] = ldF(convw, i, wbf);   // wT[ch][h][o]
    }
    if (i < 53248) l1wf[i] = ldF(l1w, i, wbf);
    if (i < 640)   l2wf[i] = ldF(l2w, i, wbf);
    if (i < 32)    cbf[i]  = ldF(convb, i, wbf);
    if (i < 10)    l2bf[i] = ldF(l2b, i, wbf);
}

// ============ CSR build via 2-level bucket sort ============
__global__ __launch_bounds__(256) void bucket_count(const int* __restrict__ ei,
                                                    int* __restrict__ bcnt,
                                                    const int* __restrict__ flags){
    __shared__ int lh[NBKT];
    int tid = threadIdx.x;
    int i64 = flags[1];
    if (tid < NBKT) lh[tid] = 0;
    __syncthreads();
    int t0 = blockIdx.x*4096;
    #pragma unroll 4
    for (int k = 0; k < 16; ++k){
        int e = t0 + k*256 + tid;
        if (e < NE) atomicAdd(&lh[edgeDst(ei,e,i64) >> 10], 1);
    }
    __syncthreads();
    if (tid < NBKT && lh[tid]) atomicAdd(&bcnt[tid], lh[tid]);
}

__global__ void bucket_scan(const int* __restrict__ bcnt, int* __restrict__ bbase,
                            int* __restrict__ bcur, int* __restrict__ offs){
    if (threadIdx.x == 0){
        int acc = 0;
        for (int b = 0; b < NBKT; ++b){
            bbase[b] = acc; bcur[b] = acc; acc += bcnt[b];
        }
        bbase[NBKT] = acc;
        offs[NND] = NE;
    }
}

__global__ __launch_bounds__(256) void bucket_scatter(const int* __restrict__ ei,
                                                      int* __restrict__ bcur,
                                                      int2* __restrict__ bedges,
                                                      const int* __restrict__ flags){
    __shared__ int lh[NBKT];
    __shared__ int lcur[NBKT];
    int tid = threadIdx.x;
    int i64 = flags[1];
    if (tid < NBKT) lh[tid] = 0;
    __syncthreads();
    int t0 = blockIdx.x*4096;
    int myd[16], mys[16];
    int cnt = 0;
    #pragma unroll 4
    for (int k = 0; k < 16; ++k){
        int e = t0 + k*256 + tid;
        if (e < NE){
            int d = edgeDst(ei,e,i64), s_ = edgeSrc(ei,e,i64);
            myd[cnt] = d; mys[cnt] = s_; ++cnt;
            atomicAdd(&lh[d >> 10], 1);
        }
    }
    __syncthreads();
    if (tid < NBKT) lcur[tid] = lh[tid] ? atomicAdd(&bcur[tid], lh[tid]) : 0;
    __syncthreads();
    for (int k = 0; k < cnt; ++k){
        int b = myd[k] >> 10;
        int p = atomicAdd(&lcur[b], 1);
        bedges[p] = make_int2(mys[k], myd[k]);
    }
}

__global__ __launch_bounds__(1024) void csr_finalize(const int2* __restrict__ bedges,
                                                     const int* __restrict__ bbase,
                                                     int* __restrict__ offs,
                                                     int* __restrict__ csr){
    __shared__ int hist[1024];
    int b = blockIdx.x;
    int tid = threadIdx.x;
    int dst0 = b << 10;
    int nd = NND - dst0; if (nd > 1024) nd = 1024;
    int e0 = bbase[b], e1 = bbase[b+1];
    hist[tid] = 0;
    __syncthreads();
    for (int e = e0 + tid; e < e1; e += 1024)
        atomicAdd(&hist[bedges[e].y - dst0], 1);
    __syncthreads();
    int own = hist[tid];
    for (int st = 1; st < 1024; st <<= 1){
        int v = (tid >= st) ? hist[tid-st] : 0;
        __syncthreads();
        hist[tid] += v;
        __syncthreads();
    }
    int excl = hist[tid] - own;
    if (tid < nd) offs[dst0 + tid] = e0 + excl;
    __syncthreads();
    hist[tid] = excl;
    __syncthreads();
    for (int e = e0 + tid; e < e1; e += 1024){
        int2 ed = bedges[e];
        int p = atomicAdd(&hist[ed.y - dst0], 1);
        csr[e0 + p] = ed.x;
    }
}

// ---- dual GEMM v3: coalesced [k][f] fp32 weights, 8 nodes/thread, float4 LDS in ----
template<int K>
__global__ __launch_bounds__(256) void dualgemm3_kernel(
    const void* __restrict__ in, const float* __restrict__ WlF,
    const float* __restrict__ WrF, const float* __restrict__ bf,
    float* __restrict__ y, float* __restrict__ z,
    const int* __restrict__ flags, int inIsF32)
{
    __shared__ float inR[32*K];
    int isbf = inIsF32 ? 0 : flags[0];
    int tid = threadIdx.x;
    int base = blockIdx.x * 32;
    for (int i = tid; i < 32*K; i += 256){
        int r = i / K, c = i - r*K;
        int node = base + r;
        inR[i] = (node < NND) ? ldF(in, (size_t)node*K + c, isbf) : 0.f;
    }
    __syncthreads();
    int f = tid & 63, ng = tid >> 6;
    float ay[8] = {0,0,0,0,0,0,0,0}, az[8] = {0,0,0,0,0,0,0,0};
    const float4* inR4 = (const float4*)(inR + ng*8*K);   // this group's 8 node rows
    #pragma unroll 2
    for (int k4 = 0; k4 < K/4; ++k4){
        int k = k4*4;
        // coalesced: lane f -> one 256B segment per load
        float wl0 = WlF[(k+0)*NH + f], wl1 = WlF[(k+1)*NH + f];
        float wl2 = WlF[(k+2)*NH + f], wl3 = WlF[(k+3)*NH + f];
        float wr0 = WrF[(k+0)*NH + f], wr1 = WrF[(k+1)*NH + f];
        float wr2 = WrF[(k+2)*NH + f], wr3 = WrF[(k+3)*NH + f];
        #pragma unroll
        for (int n = 0; n < 8; ++n){
            float4 v = inR4[n*(K/4) + k4];                // broadcast within wave
            ay[n] += wl0*v.x + wl1*v.y + wl2*v.z + wl3*v.w;
            az[n] += wr0*v.x + wr1*v.y + wr2*v.z + wr3*v.w;
        }
    }
    float bv = bf[f];
    #pragma unroll
    for (int n = 0; n < 8; ++n){
        int node = base + ng*8 + n;
        if (node < NND){
            y[(size_t)node*NH + f] = ay[n];
            z[(size_t)node*NH + f] = az[n] + bv;
        }
    }
}

// -------- gather v2: 4 feature-chunk passes; per-pass y-slice (3.2MB) is L2-resident --
__global__ __launch_bounds__(256) void gather2_kernel(
    const float4* __restrict__ y4, const int* __restrict__ offs,
    const int* __restrict__ csr, const float4* __restrict__ z4,
    float4* __restrict__ out4)
{
    int t = blockIdx.x*256 + threadIdx.x;
    int node = t >> 2;
    if (node >= NND) return;
    int qq = (blockIdx.y << 2) | (t & 3);      // float4 index within 16-float4 row
    int o0 = offs[node], o1 = offs[node+1];
    float ax=0.f, ayv=0.f, azv=0.f, aw=0.f;
    int e = o0;
    for (; e + 3 < o1; e += 4){
        int s0 = csr[e], s1 = csr[e+1], s2 = csr[e+2], s3 = csr[e+3];
        float4 a = y4[(size_t)s0*16 + qq];
        float4 b = y4[(size_t)s1*16 + qq];
        float4 c = y4[(size_t)s2*16 + qq];
        float4 d = y4[(size_t)s3*16 + qq];
        ax  += a.x + b.x + c.x + d.x;
        ayv += a.y + b.y + c.y + d.y;
        azv += a.z + b.z + c.z + d.z;
        aw  += a.w + b.w + c.w + d.w;
    }
    for (; e < o1; ++e){
        float4 a = y4[(size_t)csr[e]*16 + qq];
        ax += a.x; ayv += a.y; azv += a.z; aw += a.w;
    }
    float dd = (float)(o1 - o0); dd = dd > 1.f ? dd : 1.f;
    float inv = 1.f / dd;
    float4 zz = z4[(size_t)node*16 + qq];
    float4 v;
    v.x = ax *inv + zz.x; v.y = ayv*inv + zz.y;
    v.z = azv*inv + zz.z; v.w = aw *inv + zz.w;
    v.x = v.x > 0.f ? v.x : 0.f;  v.y = v.y > 0.f ? v.y : 0.f;
    v.z = v.z > 0.f ? v.z : 0.f;  v.w = v.w > 0.f ? v.w : 0.f;
    out4[(size_t)node*16 + qq] = v;
}

// ------ head v3: bitonic-sort top-30 (all 256 threads) + conv + fc1 + fc2 + lsm ----
__global__ __launch_bounds__(256) void head3_kernel(
    const float* __restrict__ h3, const int* __restrict__ starts,
    const float* __restrict__ wT, const float* __restrict__ cbf,
    const float* __restrict__ l1wf, const float* __restrict__ l1bf,
    const float* __restrict__ l2wf, const float* __restrict__ l2bf,
    float* __restrict__ outp)
{
    __shared__ u64  keys[256];
    __shared__ int  sel[KP];
    __shared__ float pT[64*32];          // pT[ch][rank], ranks 30,31 zeroed
    __shared__ float part[8*832];
    __shared__ float cbuf[832];
    __shared__ float fbuf[NH];
    __shared__ float logitsS[NCLS];
    int g = blockIdx.x, tid = threadIdx.x;
    int s = starts[g], e = starts[g+1];
    int cnt = e - s; if (cnt > 256) cnt = 256; if (cnt < 0) cnt = 0;

    u64 key = 0xFFFFFFFFFFFFFFFFull;
    if (tid < cnt){
        float v = h3[(size_t)(s+tid)*NH + 63];
        unsigned u = __float_as_uint(v);
        unsigned m = (u & 0x80000000u) ? ~u : (u | 0x80000000u);
        unsigned d = ~m;
        key = ((u64)d << 32) | (unsigned)tid;
    }
    keys[tid] = key;
    __syncthreads();
    for (int k = 2; k <= 256; k <<= 1){
        for (int j = k >> 1; j > 0; j >>= 1){
            int partner = tid ^ j;
            u64 a = keys[tid], b = keys[partner];
            bool up = ((tid & k) == 0);
            bool amin = a < b;
            u64 keep;
            if (partner > tid) keep = (up == amin) ? a : b;
            else               keep = (up == amin) ? b : a;
            __syncthreads();
            keys[tid] = keep;
            __syncthreads();
        }
    }
    if (tid < KP){
        u64 kk = keys[tid];
        sel[tid] = ((unsigned)(kk >> 32) == 0xFFFFFFFFu) ? -1 : (int)(kk & 0xFFFFFFFFu);
    }
    if (tid < 64){ pT[tid*32 + 30] = 0.f; pT[tid*32 + 31] = 0.f; }
    __syncthreads();
    for (int i = tid; i < KP*64; i += 256){
        int r = i >> 6, f = i & 63;
        int li = sel[r];
        pT[f*32 + r] = (li >= 0) ? h3[(size_t)(s+li)*NH + f] : 0.f;
    }
    __syncthreads();

    int o = tid & 31, chg = tid >> 5;
    float acc[26];
    #pragma unroll
    for (int t = 0; t < 26; ++t) acc[t] = 0.f;
    for (int c8 = 0; c8 < 8; ++c8){
        int ch = chg*8 + c8;
        const float4* prow = (const float4*)&pT[ch*32];
        float p[32];
        #pragma unroll
        for (int q = 0; q < 8; ++q){
            float4 v = prow[q];
            p[4*q]=v.x; p[4*q+1]=v.y; p[4*q+2]=v.z; p[4*q+3]=v.w;
        }
        const float* wrow = &wT[ch*160 + o];
        #pragma unroll
        for (int h = 0; h < 5; ++h){
            float wv = wrow[h*32];
            #pragma unroll
            for (int t = 0; t < 26; ++t) acc[t] += p[t+h]*wv;
        }
    }
    #pragma unroll
    for (int t = 0; t < 26; ++t) part[chg*832 + o*26 + t] = acc[t];
    __syncthreads();

    for (int i = tid; i < 832; i += 256){
        int oo = i / 26;
        float a = cbf[oo];
        #pragma unroll
        for (int cg = 0; cg < 8; ++cg) a += part[cg*832 + i];
        cbuf[i] = a > 0.f ? a : 0.f;
    }
    __syncthreads();

    {   // fc1: 832 -> 64
        int p = tid >> 6, j = tid & 63;
        float a = 0.f;
        int m0 = p*208;
        #pragma unroll 4
        for (int m = m0; m < m0 + 208; ++m)
            a += cbuf[m] * l1wf[(size_t)m*NH + j];
        part[p*NH + j] = a;
    }
    __syncthreads();
    if (tid < NH){
        float v = part[tid] + part[NH+tid] + part[2*NH+tid] + part[3*NH+tid] + l1bf[tid];
        fbuf[tid] = v > 0.f ? v : 0.f;
    }
    __syncthreads();
    if (tid < NCLS){
        float a = l2bf[tid];
        #pragma unroll
        for (int j = 0; j < NH; ++j) a += fbuf[j] * l2wf[j*NCLS + tid];
        logitsS[tid] = a;
    }
    __syncthreads();
    if (tid == 0){
        float m = logitsS[0];
        for (int c = 1; c < NCLS; ++c) m = fmaxf(m, logitsS[c]);
        float ssum = 0.f;
        for (int c = 0; c < NCLS; ++c) ssum += expf(logitsS[c]-m);
        float lse = m + logf(ssum);
        for (int c = 0; c < NCLS; ++c)
            outp[(size_t)g*NCLS + c] = logitsS[c] - lse;
    }
}

extern "C" void kernel_launch(void* const* d_in, const int* in_sizes, int n_in,
                              void* d_out, int out_size, void* d_ws, size_t ws_size,
                              hipStream_t stream) {
    const void* x    = d_in[0];
    const int*  ei   = (const int*)d_in[1];
    const int*  batch= (const int*)d_in[2];
    const void *W1l=d_in[3], *b1=d_in[4],  *W1r=d_in[5];
    const void *W2l=d_in[6], *b2=d_in[7],  *W2r=d_in[8];
    const void *W3l=d_in[9], *b3=d_in[10], *W3r=d_in[11];
    const void *convw=d_in[12], *convb=d_in[13];
    const void *l1w=d_in[14], *l1b=d_in[15];
    const void *l2w=d_in[16], *l2b=d_in[17];
    float* out = (float*)d_out;

    float* wsf = (float*)d_ws;
    float* A  = wsf;                             // 50000*64
    float* Bb = A  + (size_t)NND*NH;             // 50000*64
    float* C  = Bb + (size_t)NND*NH;             // 50000*64
    int2* bedges = (int2*)(C + (size_t)NND*NH);  // 800000 int2
    float* w1lF = (float*)(bedges + NE);         // 8192
    float* w1rF = w1lF + 8192;                   // 8192
    float* w2lF = w1rF + 8192;                   // 4096
    float* w2rF = w2lF + 4096;                   // 4096
    float* w3lF = w2rF + 4096;                   // 4096
    float* w3rF = w3lF + 4096;                   // 4096
    float* b1f  = w3rF + 4096;                   // 64
    float* b2f  = b1f + 64;                      // 64
    float* b3f  = b2f + 64;                      // 64
    float* wT   = b3f + 64;                      // 10240
    float* cbf  = wT + 10240;                    // 32
    float* l1wf = cbf + 32;                      // 53248
    float* l1bf = l1wf + 53248;                  // 64
    float* l2wf = l1bf + 64;                     // 640
    float* l2bf = l2wf + 640;                    // 10 (+pad)
    int* starts = (int*)(l2bf + 16);             // 513
    int* flags  = starts + 520;                  // 2
    int* bcnt   = flags + 8;                     // 49
    int* bbase  = bcnt + 64;                     // 50
    int* bcur   = bbase + 64;                    // 49
    int* offs   = bcur + 64;                     // 50001
    int* csr    = offs + NND + 3;                // 800000

    probe_kernel<<<1, 256, 0, stream>>>((const unsigned int*)x, ei, flags);
    setup_kernel<<<(53248+255)/256, 256, 0, stream>>>(batch, starts,
        W1l, W1r, b1, W2l, W2r, b2, W3l, W3r, b3,
        convw, convb, l1w, l1b, l2w, l2b,
        w1lF, w1rF, b1f, w2lF, w2rF, b2f, w3lF, w3rF, b3f,
        wT, cbf, l1wf, l1bf, l2wf, l2bf, flags);

    // ---- CSR build via bucket sort ----
    const int NTILE = (NE + 4095)/4096;          // 196
    hipMemsetAsync(bcnt, 0, NBKT*sizeof(int), stream);
    bucket_count<<<NTILE, 256, 0, stream>>>(ei, bcnt, flags);
    bucket_scan<<<1, 64, 0, stream>>>(bcnt, bbase, bcur, offs);
    bucket_scatter<<<NTILE, 256, 0, stream>>>(ei, bcur, bedges, flags);
    csr_finalize<<<NBKT, 1024, 0, stream>>>(bedges, bbase, offs, csr);

    int gblocks32 = (NND + 31)/32;               // 1563
    dim3 ggrid((NND*4 + 255)/256, 4);            // 782 x 4 chunks

    // ---- layer 1: x -> B ----
    dualgemm3_kernel<NF><<<gblocks32,256,0,stream>>>(x, w1lF, w1rF, b1f, A, Bb, flags, 0);
    gather2_kernel<<<ggrid,256,0,stream>>>((const float4*)A, offs, csr, (const float4*)Bb, (float4*)Bb);

    // ---- layer 2: B -> C ----
    dualgemm3_kernel<NH><<<gblocks32,256,0,stream>>>(Bb, w2lF, w2rF, b2f, A, C, flags, 1);
    gather2_kernel<<<ggrid,256,0,stream>>>((const float4*)A, offs, csr, (const float4*)C, (float4*)C);

    // ---- layer 3: C -> B ----
    dualgemm3_kernel<NH><<<gblocks32,256,0,stream>>>(C, w3lF, w3rF, b3f, A, Bb, flags, 1);
    gather2_kernel<<<ggrid,256,0,stream>>>((const float4*)A, offs, csr, (const float4*)Bb, (float4*)Bb);

    // ---- head ----
    head3_kernel<<<NB,256,0,stream>>>(Bb, starts, wT, cbf, l1wf, l1bf, l2wf, l2bf, out);
}

// Round 11
// 318.009 us; speedup vs baseline: 1.6958x; 1.3385x over previous
//
#include <hip/hip_runtime.h>
#include <hip/hip_bf16.h>
#include <math.h>

#define NND 50000
#define NE 800000
#define NF 128
#define NH 64
#define NB 512
#define KP 30
#define NCLS 10
#define NBKT 49              // coarse buckets of 1024 dsts

typedef __hip_bfloat16 bf16;
typedef unsigned long long u64;
typedef unsigned short ushort_t;

__device__ __forceinline__ float ldF(const void* p, size_t i, int isbf){
    return isbf ? __bfloat162float(((const bf16*)p)[i]) : ((const float*)p)[i];
}

// fp32 -> bf16 bits, round-to-nearest-even (matches HW/numpy)
__device__ __forceinline__ ushort_t f2bf(float v){
    unsigned u = __float_as_uint(v);
    unsigned r = u + 0x7FFFu + ((u >> 16) & 1u);
    return (ushort_t)(r >> 16);
}

// ---------------- dtype probe: flags[0]=floats-are-bf16, flags[1]=ints-are-int64 ----
__global__ void probe_kernel(const unsigned int* __restrict__ xw,
                             const int* __restrict__ ew, int* __restrict__ flags){
    __shared__ int cF, cI;
    if (threadIdx.x == 0){ cF = 0; cI = 0; }
    __syncthreads();
    unsigned int w = xw[threadIdx.x];
    int ex = (int)((w >> 7) & 0xFF);
    if (ex >= 100 && ex <= 140) atomicAdd(&cF, 1);
    if (ew[2*threadIdx.x + 1] == 0) atomicAdd(&cI, 1);
    __syncthreads();
    if (threadIdx.x == 0){
        flags[0] = (cF >= 128) ? 1 : 0;
        flags[1] = (cI >= 192) ? 1 : 0;
    }
}

__device__ __forceinline__ int edgeSrc(const int* ei, int e, int i64){
    return i64 ? ei[2*e] : ei[e];
}
__device__ __forceinline__ int edgeDst(const int* ei, int e, int i64){
    return i64 ? ei[2*NE + 2*e] : ei[NE + e];
}

// ------------- setup: per-graph starts + fp32 head-weight preconvert ------
__global__ __launch_bounds__(256) void setup_kernel(
    const int* __restrict__ batch, int* __restrict__ starts,
    const void* convw, const void* convb,
    const void* l1w, const void* l1b, const void* l2w, const void* l2b,
    float* __restrict__ wT, float* __restrict__ cbf,
    float* __restrict__ l1wf, float* __restrict__ l1bf,
    float* __restrict__ l2wf, float* __restrict__ l2bf,
    const int* __restrict__ flags)
{
    int wbf = flags[0];
    int i64 = flags[1];
    int i = blockIdx.x*256 + threadIdx.x;
    if (i < NND){
        int b  = i64 ? batch[2*i] : batch[i];
        int pb = (i == 0) ? -1 : (i64 ? batch[2*(i-1)] : batch[i-1]);
        for (int g = pb+1; g <= b; ++g) starts[g] = i;
        if (i == NND-1) for (int g = b+1; g <= NB; ++g) starts[g] = NND;
    }
    if (i < 10240){
        int o = i / 320, rem = i - o*320, ch = rem/5, h = rem - ch*5;
        wT[ch*160 + h*32 + o] = ldF(convw, i, wbf);   // wT[ch][h][o]
    }
    if (i < 53248) l1wf[i] = ldF(l1w, i, wbf);
    if (i < 640)   l2wf[i] = ldF(l2w, i, wbf);
    if (i < 64)    l1bf[i] = ldF(l1b, i, wbf);
    if (i < 32)    cbf[i]  = ldF(convb, i, wbf);
    if (i < 10)    l2bf[i] = ldF(l2b, i, wbf);
}

// ============ CSR build via 2-level bucket sort (r7, measured good) ============
__global__ __launch_bounds__(256) void bucket_count(const int* __restrict__ ei,
                                                    int* __restrict__ bcnt,
                                                    const int* __restrict__ flags){
    __shared__ int lh[NBKT];
    int tid = threadIdx.x;
    int i64 = flags[1];
    if (tid < NBKT) lh[tid] = 0;
    __syncthreads();
    int t0 = blockIdx.x*4096;
    #pragma unroll 4
    for (int k = 0; k < 16; ++k){
        int e = t0 + k*256 + tid;
        if (e < NE) atomicAdd(&lh[edgeDst(ei,e,i64) >> 10], 1);
    }
    __syncthreads();
    if (tid < NBKT && lh[tid]) atomicAdd(&bcnt[tid], lh[tid]);
}

__global__ void bucket_scan(const int* __restrict__ bcnt, int* __restrict__ bbase,
                            int* __restrict__ bcur, int* __restrict__ offs){
    if (threadIdx.x == 0){
        int acc = 0;
        for (int b = 0; b < NBKT; ++b){
            bbase[b] = acc; bcur[b] = acc; acc += bcnt[b];
        }
        bbase[NBKT] = acc;
        offs[NND] = NE;
    }
}

__global__ __launch_bounds__(256) void bucket_scatter(const int* __restrict__ ei,
                                                      int* __restrict__ bcur,
                                                      int2* __restrict__ bedges,
                                                      const int* __restrict__ flags){
    __shared__ int lh[NBKT];
    __shared__ int lcur[NBKT];
    int tid = threadIdx.x;
    int i64 = flags[1];
    if (tid < NBKT) lh[tid] = 0;
    __syncthreads();
    int t0 = blockIdx.x*4096;
    int myd[16], mys[16];
    int cnt = 0;
    #pragma unroll 4
    for (int k = 0; k < 16; ++k){
        int e = t0 + k*256 + tid;
        if (e < NE){
            int d = edgeDst(ei,e,i64), s_ = edgeSrc(ei,e,i64);
            myd[cnt] = d; mys[cnt] = s_; ++cnt;
            atomicAdd(&lh[d >> 10], 1);
        }
    }
    __syncthreads();
    if (tid < NBKT) lcur[tid] = lh[tid] ? atomicAdd(&bcur[tid], lh[tid]) : 0;
    __syncthreads();
    for (int k = 0; k < cnt; ++k){
        int b = myd[k] >> 10;
        int p = atomicAdd(&lcur[b], 1);
        bedges[p] = make_int2(mys[k], myd[k]);
    }
}

__global__ __launch_bounds__(1024) void csr_finalize(const int2* __restrict__ bedges,
                                                     const int* __restrict__ bbase,
                                                     int* __restrict__ offs,
                                                     int* __restrict__ csr){
    __shared__ int hist[1024];
    int b = blockIdx.x;
    int tid = threadIdx.x;
    int dst0 = b << 10;
    int nd = NND - dst0; if (nd > 1024) nd = 1024;
    int e0 = bbase[b], e1 = bbase[b+1];
    hist[tid] = 0;
    __syncthreads();
    for (int e = e0 + tid; e < e1; e += 1024)
        atomicAdd(&hist[bedges[e].y - dst0], 1);
    __syncthreads();
    int own = hist[tid];
    for (int st = 1; st < 1024; st <<= 1){
        int v = (tid >= st) ? hist[tid-st] : 0;
        __syncthreads();
        hist[tid] += v;
        __syncthreads();
    }
    int excl = hist[tid] - own;
    if (tid < nd) offs[dst0 + tid] = e0 + excl;
    __syncthreads();
    hist[tid] = excl;
    __syncthreads();
    for (int e = e0 + tid; e < e1; e += 1024){
        int2 ed = bedges[e];
        int p = atomicAdd(&hist[ed.y - dst0], 1);
        csr[e0 + p] = ed.x;
    }
}

// ---------------- dual GEMM (r7 structure): y(bf16) = h@Wl ; z(f32) = h@Wr + b ------
// Lesson R8/R9: stream weights typed [k][f] (lane=f -> coalesced 128B), 16 nodes/blk,
// 8KB LDS, high occupancy. Do NOT transpose weights; do NOT fatten register tiles.
template<int K, typename TW>
__device__ __forceinline__ void dual_loop(const TW* __restrict__ Wl, const TW* __restrict__ Wr,
                                          const float* r0, const float* r1,
                                          const float* r2, const float* r3,
                                          int f, float* ay, float* az){
    #pragma unroll 4
    for (int k = 0; k < K; ++k){
        float wl = (float)Wl[(size_t)k*NH + f];
        float wr = (float)Wr[(size_t)k*NH + f];
        float v0 = r0[k], v1 = r1[k], v2 = r2[k], v3 = r3[k];
        ay[0] += wl*v0; ay[1] += wl*v1; ay[2] += wl*v2; ay[3] += wl*v3;
        az[0] += wr*v0; az[1] += wr*v1; az[2] += wr*v2; az[3] += wr*v3;
    }
}

template<int K>
__global__ __launch_bounds__(256) void dualgemm_kernel(
    const void* __restrict__ in, const void* __restrict__ Wl_,
    const void* __restrict__ Wr_, const void* __restrict__ bias,
    ushort_t* __restrict__ ybf, float* __restrict__ z,
    const int* __restrict__ flags, int inIsF32)
{
    __shared__ float inR[16*K];
    int isbf = inIsF32 ? 0 : flags[0];
    int wbf  = flags[0];
    int tid = threadIdx.x;
    int base = blockIdx.x * 16;
    for (int i = tid; i < 16*K; i += 256){
        int r = i / K, c = i - r*K;
        int node = base + r;
        inR[i] = (node < NND) ? ldF(in, (size_t)node*K + c, isbf) : 0.f;
    }
    __syncthreads();
    int f = tid & 63, ng = tid >> 6;
    float ay[4] = {0,0,0,0}, az[4] = {0,0,0,0};
    const float* r0 = &inR[(ng*4+0)*K];
    const float* r1 = &inR[(ng*4+1)*K];
    const float* r2 = &inR[(ng*4+2)*K];
    const float* r3 = &inR[(ng*4+3)*K];
    if (wbf) dual_loop<K>((const bf16*)Wl_, (const bf16*)Wr_, r0,r1,r2,r3, f, ay, az);
    else     dual_loop<K>((const float*)Wl_,(const float*)Wr_, r0,r1,r2,r3, f, ay, az);
    float bv = ldF(bias, f, wbf);
    #pragma unroll
    for (int j = 0; j < 4; ++j){
        int node = base + ng*4 + j;
        if (node < NND){
            ybf[(size_t)node*NH + f] = f2bf(ay[j]);   // bf16 store (RNE)
            z[(size_t)node*NH + f] = az[j] + bv;
        }
    }
}

// ---------------- gather (single-pass, bf16 y): out = relu(mean_csr(y) + z) ------
// 16 lanes/node, 8B (4×bf16) per lane per edge -> 128B contiguous per edge row.
__device__ __forceinline__ void acc4(uint2 u, float& a0, float& a1, float& a2, float& a3){
    a0 += __uint_as_float(u.x << 16);
    a1 += __uint_as_float(u.x & 0xFFFF0000u);
    a2 += __uint_as_float(u.y << 16);
    a3 += __uint_as_float(u.y & 0xFFFF0000u);
}

__global__ __launch_bounds__(256) void gather_kernel(
    const ushort_t* __restrict__ yb, const int* __restrict__ offs,
    const int* __restrict__ csr, const float* __restrict__ z,
    float* __restrict__ out)
{
    int t = blockIdx.x*256 + threadIdx.x;
    int node = t >> 4;
    int q = t & 15;
    if (node >= NND) return;
    int o0 = offs[node], o1 = offs[node+1];
    float a0=0.f, a1=0.f, a2=0.f, a3=0.f;
    int e = o0;
    for (; e + 3 < o1; e += 4){
        int s0 = csr[e], s1 = csr[e+1], s2 = csr[e+2], s3 = csr[e+3];
        uint2 u0 = *(const uint2*)&yb[(size_t)s0*NH + q*4];
        uint2 u1 = *(const uint2*)&yb[(size_t)s1*NH + q*4];
        uint2 u2 = *(const uint2*)&yb[(size_t)s2*NH + q*4];
        uint2 u3 = *(const uint2*)&yb[(size_t)s3*NH + q*4];
        acc4(u0, a0,a1,a2,a3); acc4(u1, a0,a1,a2,a3);
        acc4(u2, a0,a1,a2,a3); acc4(u3, a0,a1,a2,a3);
    }
    for (; e < o1; ++e){
        uint2 u = *(const uint2*)&yb[(size_t)csr[e]*NH + q*4];
        acc4(u, a0,a1,a2,a3);
    }
    float dd = (float)(o1 - o0); dd = dd > 1.f ? dd : 1.f;
    float inv = 1.f / dd;
    size_t base = (size_t)node*NH + q*4;
    float4 zz = *(const float4*)&z[base];
    float4 v;
    v.x = a0*inv + zz.x; v.y = a1*inv + zz.y;
    v.z = a2*inv + zz.z; v.w = a3*inv + zz.w;
    v.x = v.x > 0.f ? v.x : 0.f;  v.y = v.y > 0.f ? v.y : 0.f;
    v.z = v.z > 0.f ? v.z : 0.f;  v.w = v.w > 0.f ? v.w : 0.f;
    *(float4*)&out[base] = v;
}

// ------ head v3: bitonic-sort top-30 (all 256 threads) + conv + fc1 + fc2 + lsm ----
__global__ __launch_bounds__(256) void head3_kernel(
    const float* __restrict__ h3, const int* __restrict__ starts,
    const float* __restrict__ wT, const float* __restrict__ cbf,
    const float* __restrict__ l1wf, const float* __restrict__ l1bf,
    const float* __restrict__ l2wf, const float* __restrict__ l2bf,
    float* __restrict__ outp)
{
    __shared__ u64  keys[256];
    __shared__ int  sel[KP];
    __shared__ float pT[64*32];          // pT[ch][rank], ranks 30,31 zeroed
    __shared__ float part[8*832];
    __shared__ float cbuf[832];
    __shared__ float fbuf[NH];
    __shared__ float logitsS[NCLS];
    int g = blockIdx.x, tid = threadIdx.x;
    int s = starts[g], e = starts[g+1];
    int cnt = e - s; if (cnt > 256) cnt = 256; if (cnt < 0) cnt = 0;

    u64 key = 0xFFFFFFFFFFFFFFFFull;
    if (tid < cnt){
        float v = h3[(size_t)(s+tid)*NH + 63];
        unsigned u = __float_as_uint(v);
        unsigned m = (u & 0x80000000u) ? ~u : (u | 0x80000000u);
        unsigned d = ~m;
        key = ((u64)d << 32) | (unsigned)tid;
    }
    keys[tid] = key;
    __syncthreads();
    for (int k = 2; k <= 256; k <<= 1){
        for (int j = k >> 1; j > 0; j >>= 1){
            int partner = tid ^ j;
            u64 a = keys[tid], b = keys[partner];
            bool up = ((tid & k) == 0);
            bool amin = a < b;
            u64 keep;
            if (partner > tid) keep = (up == amin) ? a : b;
            else               keep = (up == amin) ? b : a;
            __syncthreads();
            keys[tid] = keep;
            __syncthreads();
        }
    }
    if (tid < KP){
        u64 kk = keys[tid];
        sel[tid] = ((unsigned)(kk >> 32) == 0xFFFFFFFFu) ? -1 : (int)(kk & 0xFFFFFFFFu);
    }
    if (tid < 64){ pT[tid*32 + 30] = 0.f; pT[tid*32 + 31] = 0.f; }
    __syncthreads();
    for (int i = tid; i < KP*64; i += 256){
        int r = i >> 6, f = i & 63;
        int li = sel[r];
        pT[f*32 + r] = (li >= 0) ? h3[(size_t)(s+li)*NH + f] : 0.f;
    }
    __syncthreads();

    int o = tid & 31, chg = tid >> 5;
    float acc[26];
    #pragma unroll
    for (int t = 0; t < 26; ++t) acc[t] = 0.f;
    for (int c8 = 0; c8 < 8; ++c8){
        int ch = chg*8 + c8;
        const float4* prow = (const float4*)&pT[ch*32];
        float p[32];
        #pragma unroll
        for (int q = 0; q < 8; ++q){
            float4 v = prow[q];
            p[4*q]=v.x; p[4*q+1]=v.y; p[4*q+2]=v.z; p[4*q+3]=v.w;
        }
        const float* wrow = &wT[ch*160 + o];
        #pragma unroll
        for (int h = 0; h < 5; ++h){
            float wv = wrow[h*32];
            #pragma unroll
            for (int t = 0; t < 26; ++t) acc[t] += p[t+h]*wv;
        }
    }
    #pragma unroll
    for (int t = 0; t < 26; ++t) part[chg*832 + o*26 + t] = acc[t];
    __syncthreads();

    for (int i = tid; i < 832; i += 256){
        int oo = i / 26;
        float a = cbf[oo];
        #pragma unroll
        for (int cg = 0; cg < 8; ++cg) a += part[cg*832 + i];
        cbuf[i] = a > 0.f ? a : 0.f;
    }
    __syncthreads();

    {   // fc1: 832 -> 64
        int p = tid >> 6, j = tid & 63;
        float a = 0.f;
        int m0 = p*208;
        #pragma unroll 4
        for (int m = m0; m < m0 + 208; ++m)
            a += cbuf[m] * l1wf[(size_t)m*NH + j];
        part[p*NH + j] = a;
    }
    __syncthreads();
    if (tid < NH){
        float v = part[tid] + part[NH+tid] + part[2*NH+tid] + part[3*NH+tid] + l1bf[tid];
        fbuf[tid] = v > 0.f ? v : 0.f;
    }
    __syncthreads();
    if (tid < NCLS){
        float a = l2bf[tid];
        #pragma unroll
        for (int j = 0; j < NH; ++j) a += fbuf[j] * l2wf[j*NCLS + tid];
        logitsS[tid] = a;
    }
    __syncthreads();
    if (tid == 0){
        float m = logitsS[0];
        for (int c = 1; c < NCLS; ++c) m = fmaxf(m, logitsS[c]);
        float ssum = 0.f;
        for (int c = 0; c < NCLS; ++c) ssum += expf(logitsS[c]-m);
        float lse = m + logf(ssum);
        for (int c = 0; c < NCLS; ++c)
            outp[(size_t)g*NCLS + c] = logitsS[c] - lse;
    }
}

extern "C" void kernel_launch(void* const* d_in, const int* in_sizes, int n_in,
                              void* d_out, int out_size, void* d_ws, size_t ws_size,
                              hipStream_t stream) {
    const void* x    = d_in[0];
    const int*  ei   = (const int*)d_in[1];
    const int*  batch= (const int*)d_in[2];
    const void *W1l=d_in[3], *b1=d_in[4],  *W1r=d_in[5];
    const void *W2l=d_in[6], *b2=d_in[7],  *W2r=d_in[8];
    const void *W3l=d_in[9], *b3=d_in[10], *W3r=d_in[11];
    const void *convw=d_in[12], *convb=d_in[13];
    const void *l1w=d_in[14], *l1b=d_in[15];
    const void *l2w=d_in[16], *l2b=d_in[17];
    float* out = (float*)d_out;

    float* wsf = (float*)d_ws;
    float* A  = wsf;                             // y as bf16 (uses half of NND*NH floats)
    float* Bb = A  + (size_t)NND*NH;             // 50000*64 f32
    float* C  = Bb + (size_t)NND*NH;             // 50000*64 f32
    int2* bedges = (int2*)(C + (size_t)NND*NH);  // 800000 int2
    float* wT   = (float*)(bedges + NE);         // 10240
    float* cbf  = wT + 10240;                    // 32
    float* l1wf = cbf + 32;                      // 53248
    float* l1bf = l1wf + 53248;                  // 64
    float* l2wf = l1bf + 64;                     // 640
    float* l2bf = l2wf + 640;                    // 10 (+pad)
    int* starts = (int*)(l2bf + 16);             // 513
    int* flags  = starts + 520;                  // 2
    int* bcnt   = flags + 8;                     // 49
    int* bbase  = bcnt + 64;                     // 50
    int* bcur   = bbase + 64;                    // 49
    int* offs   = bcur + 64;                     // 50001
    int* csr    = offs + NND + 3;                // 800000
    ushort_t* ybf = (ushort_t*)A;

    probe_kernel<<<1, 256, 0, stream>>>((const unsigned int*)x, ei, flags);
    setup_kernel<<<(53248+255)/256, 256, 0, stream>>>(batch, starts,
        convw, convb, l1w, l1b, l2w, l2b,
        wT, cbf, l1wf, l1bf, l2wf, l2bf, flags);

    // ---- CSR build via bucket sort ----
    const int NTILE = (NE + 4095)/4096;          // 196
    (void)hipMemsetAsync(bcnt, 0, NBKT*sizeof(int), stream);
    bucket_count<<<NTILE, 256, 0, stream>>>(ei, bcnt, flags);
    bucket_scan<<<1, 64, 0, stream>>>(bcnt, bbase, bcur, offs);
    bucket_scatter<<<NTILE, 256, 0, stream>>>(ei, bcur, bedges, flags);
    csr_finalize<<<NBKT, 1024, 0, stream>>>(bedges, bbase, offs, csr);

    int gblocks = (NND + 15)/16;                 // 3125
    int ngath   = (NND*16 + 255)/256;            // 3125

    // ---- layer 1: x -> B ----
    dualgemm_kernel<NF><<<gblocks,256,0,stream>>>(x, W1l, W1r, b1, ybf, Bb, flags, 0);
    gather_kernel<<<ngath,256,0,stream>>>(ybf, offs, csr, Bb, Bb);

    // ---- layer 2: B -> C ----
    dualgemm_kernel<NH><<<gblocks,256,0,stream>>>(Bb, W2l, W2r, b2, ybf, C, flags, 1);
    gather_kernel<<<ngath,256,0,stream>>>(ybf, offs, csr, C, C);

    // ---- layer 3: C -> B ----
    dualgemm_kernel<NH><<<gblocks,256,0,stream>>>(C, W3l, W3r, b3, ybf, Bb, flags, 1);
    gather_kernel<<<ngath,256,0,stream>>>(ybf, offs, csr, Bb, Bb);

    // ---- head ----
    head3_kernel<<<NB,256,0,stream>>>(Bb, starts, wT, cbf, l1wf, l1bf, l2wf, l2bf, out);
}

// Round 12
// 299.109 us; speedup vs baseline: 1.8029x; 1.0632x over previous
//
#include <hip/hip_runtime.h>
#include <hip/hip_bf16.h>
#include <math.h>

#define NND 50000
#define NE 800000
#define NF 128
#define NH 64
#define NB 512
#define KP 30
#define NCLS 10
#define NBKT 49              // coarse buckets of 1024 dsts

typedef __hip_bfloat16 bf16;
typedef unsigned long long u64;
typedef unsigned short ushort_t;
typedef __attribute__((ext_vector_type(8))) short bf16x8;   // 8 bf16 (4 VGPRs)
typedef __attribute__((ext_vector_type(4))) float f32x4;

__device__ __forceinline__ float ldF(const void* p, size_t i, int isbf){
    return isbf ? __bfloat162float(((const bf16*)p)[i]) : ((const float*)p)[i];
}

// fp32 -> bf16 bits, round-to-nearest-even (matches HW/numpy)
__device__ __forceinline__ ushort_t f2bf(float v){
    unsigned u = __float_as_uint(v);
    unsigned r = u + 0x7FFFu + ((u >> 16) & 1u);
    return (ushort_t)(r >> 16);
}

// ---------------- dtype probe: flags[0]=floats-are-bf16, flags[1]=ints-are-int64 ----
__global__ void probe_kernel(const unsigned int* __restrict__ xw,
                             const int* __restrict__ ew, int* __restrict__ flags){
    __shared__ int cF, cI;
    if (threadIdx.x == 0){ cF = 0; cI = 0; }
    __syncthreads();
    unsigned int w = xw[threadIdx.x];
    int ex = (int)((w >> 7) & 0xFF);
    if (ex >= 100 && ex <= 140) atomicAdd(&cF, 1);
    if (ew[2*threadIdx.x + 1] == 0) atomicAdd(&cI, 1);
    __syncthreads();
    if (threadIdx.x == 0){
        flags[0] = (cF >= 128) ? 1 : 0;
        flags[1] = (cI >= 192) ? 1 : 0;
    }
}

__device__ __forceinline__ int edgeSrc(const int* ei, int e, int i64){
    return i64 ? ei[2*e] : ei[e];
}
__device__ __forceinline__ int edgeDst(const int* ei, int e, int i64){
    return i64 ? ei[2*NE + 2*e] : ei[NE + e];
}

// ------------- setup: starts + head weights fp32 + MFMA B-frag swizzled weights -----
// wB layout: [c][t][lane][j] -> value = (n<64 ? Wl : Wr)[k][n%64],
//   k = c*32 + (lane>>4)*8 + j,  n = t*16 + (lane&15).  16B contiguous per lane.
__global__ __launch_bounds__(256) void setup_kernel(
    const int* __restrict__ batch, int* __restrict__ starts,
    const void* W1l, const void* W1r, const void* b1,
    const void* W2l, const void* W2r, const void* b2,
    const void* W3l, const void* W3r, const void* b3,
    const void* convw, const void* convb,
    const void* l1w, const void* l1b, const void* l2w, const void* l2b,
    ushort_t* __restrict__ wB1, ushort_t* __restrict__ wB2, ushort_t* __restrict__ wB3,
    float* __restrict__ b1f, float* __restrict__ b2f, float* __restrict__ b3f,
    float* __restrict__ wT, float* __restrict__ cbf,
    float* __restrict__ l1wf, float* __restrict__ l1bf,
    float* __restrict__ l2wf, float* __restrict__ l2bf,
    const int* __restrict__ flags)
{
    int wbf = flags[0];
    int i64 = flags[1];
    int i = blockIdx.x*256 + threadIdx.x;
    if (i < NND){
        int b  = i64 ? batch[2*i] : batch[i];
        int pb = (i == 0) ? -1 : (i64 ? batch[2*(i-1)] : batch[i-1]);
        for (int g = pb+1; g <= b; ++g) starts[g] = i;
        if (i == NND-1) for (int g = b+1; g <= NB; ++g) starts[g] = NND;
    }
    // MFMA B-frag swizzle
    {
        int j = i & 7, lane = (i >> 3) & 63, t = (i >> 9) & 7, c = i >> 12;
        int k = c*32 + (lane >> 4)*8 + j;
        int n = t*16 + (lane & 15);
        if (i < 16384){   // layer 1, K=128, KC=4
            float v = (n < 64) ? ldF(W1l, (size_t)k*NH + n, wbf)
                               : ldF(W1r, (size_t)k*NH + (n-64), wbf);
            wB1[i] = f2bf(v);
        }
        if (i < 8192){    // layers 2,3, K=64, KC=2
            float v2 = (n < 64) ? ldF(W2l, (size_t)k*NH + n, wbf)
                                : ldF(W2r, (size_t)k*NH + (n-64), wbf);
            float v3 = (n < 64) ? ldF(W3l, (size_t)k*NH + n, wbf)
                                : ldF(W3r, (size_t)k*NH + (n-64), wbf);
            wB2[i] = f2bf(v2);
            wB3[i] = f2bf(v3);
        }
    }
    if (i < 64){
        b1f[i] = ldF(b1, i, wbf);
        b2f[i] = ldF(b2, i, wbf);
        b3f[i] = ldF(b3, i, wbf);
        l1bf[i] = ldF(l1b, i, wbf);
    }
    if (i < 10240){
        int o = i / 320, rem = i - o*320, ch = rem/5, h = rem - ch*5;
        wT[ch*160 + h*32 + o] = ldF(convw, i, wbf);   // wT[ch][h][o]
    }
    if (i < 53248) l1wf[i] = ldF(l1w, i, wbf);
    if (i < 640)   l2wf[i] = ldF(l2w, i, wbf);
    if (i < 32)    cbf[i]  = ldF(convb, i, wbf);
    if (i < 10)    l2bf[i] = ldF(l2b, i, wbf);
}

// ============ CSR build via 2-level bucket sort (r7, measured good) ============
__global__ __launch_bounds__(256) void bucket_count(const int* __restrict__ ei,
                                                    int* __restrict__ bcnt,
                                                    const int* __restrict__ flags){
    __shared__ int lh[NBKT];
    int tid = threadIdx.x;
    int i64 = flags[1];
    if (tid < NBKT) lh[tid] = 0;
    __syncthreads();
    int t0 = blockIdx.x*4096;
    #pragma unroll 4
    for (int k = 0; k < 16; ++k){
        int e = t0 + k*256 + tid;
        if (e < NE) atomicAdd(&lh[edgeDst(ei,e,i64) >> 10], 1);
    }
    __syncthreads();
    if (tid < NBKT && lh[tid]) atomicAdd(&bcnt[tid], lh[tid]);
}

__global__ void bucket_scan(const int* __restrict__ bcnt, int* __restrict__ bbase,
                            int* __restrict__ bcur, int* __restrict__ offs){
    if (threadIdx.x == 0){
        int acc = 0;
        for (int b = 0; b < NBKT; ++b){
            bbase[b] = acc; bcur[b] = acc; acc += bcnt[b];
        }
        bbase[NBKT] = acc;
        offs[NND] = NE;
    }
}

__global__ __launch_bounds__(256) void bucket_scatter(const int* __restrict__ ei,
                                                      int* __restrict__ bcur,
                                                      int2* __restrict__ bedges,
                                                      const int* __restrict__ flags){
    __shared__ int lh[NBKT];
    __shared__ int lcur[NBKT];
    int tid = threadIdx.x;
    int i64 = flags[1];
    if (tid < NBKT) lh[tid] = 0;
    __syncthreads();
    int t0 = blockIdx.x*4096;
    int myd[16], mys[16];
    int cnt = 0;
    #pragma unroll 4
    for (int k = 0; k < 16; ++k){
        int e = t0 + k*256 + tid;
        if (e < NE){
            int d = edgeDst(ei,e,i64), s_ = edgeSrc(ei,e,i64);
            myd[cnt] = d; mys[cnt] = s_; ++cnt;
            atomicAdd(&lh[d >> 10], 1);
        }
    }
    __syncthreads();
    if (tid < NBKT) lcur[tid] = lh[tid] ? atomicAdd(&bcur[tid], lh[tid]) : 0;
    __syncthreads();
    for (int k = 0; k < cnt; ++k){
        int b = myd[k] >> 10;
        int p = atomicAdd(&lcur[b], 1);
        bedges[p] = make_int2(mys[k], myd[k]);
    }
}

__global__ __launch_bounds__(1024) void csr_finalize(const int2* __restrict__ bedges,
                                                     const int* __restrict__ bbase,
                                                     int* __restrict__ offs,
                                                     int* __restrict__ csr){
    __shared__ int hist[1024];
    int b = blockIdx.x;
    int tid = threadIdx.x;
    int dst0 = b << 10;
    int nd = NND - dst0; if (nd > 1024) nd = 1024;
    int e0 = bbase[b], e1 = bbase[b+1];
    hist[tid] = 0;
    __syncthreads();
    for (int e = e0 + tid; e < e1; e += 1024)
        atomicAdd(&hist[bedges[e].y - dst0], 1);
    __syncthreads();
    int own = hist[tid];
    for (int st = 1; st < 1024; st <<= 1){
        int v = (tid >= st) ? hist[tid-st] : 0;
        __syncthreads();
        hist[tid] += v;
        __syncthreads();
    }
    int excl = hist[tid] - own;
    if (tid < nd) offs[dst0 + tid] = e0 + excl;
    __syncthreads();
    hist[tid] = excl;
    __syncthreads();
    for (int e = e0 + tid; e < e1; e += 1024){
        int2 ed = bedges[e];
        int p = atomicAdd(&hist[ed.y - dst0], 1);
        csr[e0 + p] = ed.x;
    }
}

// ------------- MFMA dual GEMM: [y|z](128 cols) = h(bf16) @ [Wl|Wr] + [0|b] --------
// 64 nodes/block, 4 waves M-split; A from LDS (row pad +8 ushorts -> 2-way = free);
// B frags from pre-swizzled global (L1-resident 16/32KB), 16B/lane coalesced.
template<int K>
__global__ __launch_bounds__(256) void mfma_dualgemm(
    const void* __restrict__ in, const ushort_t* __restrict__ wB,
    const float* __restrict__ bfp, ushort_t* __restrict__ ybf,
    float* __restrict__ z, const int* __restrict__ flags, int inIsBf)
{
    constexpr int KC = K/32;
    constexpr int RS = K + 8;                  // LDS row stride (ushorts)
    __shared__ ushort_t hA[64*RS];
    int tid = threadIdx.x;
    int isbf = inIsBf ? 1 : flags[0];
    int base = blockIdx.x * 64;
    for (int i = tid; i < 64*K; i += 256){
        int r = i / K, c = i - r*K;
        int node = base + r;
        float v = (node < NND) ? ldF(in, (size_t)node*K + c, isbf) : 0.f;
        hA[r*RS + c] = f2bf(v);
    }
    __syncthreads();
    int lane = tid & 63, w = tid >> 6;
    int n16 = lane & 15, quad = lane >> 4;
    f32x4 acc[8];
    #pragma unroll
    for (int t = 0; t < 8; ++t) acc[t] = (f32x4){0.f,0.f,0.f,0.f};
    const bf16x8* bp = (const bf16x8*)wB;
    #pragma unroll
    for (int c = 0; c < KC; ++c){
        bf16x8 a = *(const bf16x8*)&hA[(w*16 + n16)*RS + c*32 + quad*8];
        #pragma unroll
        for (int t = 0; t < 8; ++t){
            bf16x8 b = bp[(c*8 + t)*64 + lane];
            acc[t] = __builtin_amdgcn_mfma_f32_16x16x32_bf16(a, b, acc[t], 0, 0, 0);
        }
    }
    // D layout: col(n16)=lane&15, row = quad*4 + reg  [m89/m91 verified]
    #pragma unroll
    for (int t = 0; t < 8; ++t){
        int f = (t & 3)*16 + n16;
        float bv = (t >= 4) ? bfp[f] : 0.f;
        #pragma unroll
        for (int r = 0; r < 4; ++r){
            int node = base + w*16 + quad*4 + r;
            if (node < NND){
                if (t < 4) ybf[(size_t)node*NH + f] = f2bf(acc[t][r]);
                else       z[(size_t)node*NH + f] = acc[t][r] + bv;
            }
        }
    }
}

// ---------------- gather (bf16 y): out = relu(mean_csr(y) + z); out bf16 or f32 ----
__device__ __forceinline__ void acc4(uint2 u, float& a0, float& a1, float& a2, float& a3){
    a0 += __uint_as_float(u.x << 16);
    a1 += __uint_as_float(u.x & 0xFFFF0000u);
    a2 += __uint_as_float(u.y << 16);
    a3 += __uint_as_float(u.y & 0xFFFF0000u);
}

__global__ __launch_bounds__(256) void gather_kernel(
    const ushort_t* __restrict__ yb, const int* __restrict__ offs,
    const int* __restrict__ csr, const float* __restrict__ z,
    float* __restrict__ outf, ushort_t* __restrict__ outb, int writeBf)
{
    int t = blockIdx.x*256 + threadIdx.x;
    int node = t >> 4;
    int q = t & 15;
    if (node >= NND) return;
    int o0 = offs[node], o1 = offs[node+1];
    float a0=0.f, a1=0.f, a2=0.f, a3=0.f;
    int e = o0;
    for (; e + 3 < o1; e += 4){
        int s0 = csr[e], s1 = csr[e+1], s2 = csr[e+2], s3 = csr[e+3];
        uint2 u0 = *(const uint2*)&yb[(size_t)s0*NH + q*4];
        uint2 u1 = *(const uint2*)&yb[(size_t)s1*NH + q*4];
        uint2 u2 = *(const uint2*)&yb[(size_t)s2*NH + q*4];
        uint2 u3 = *(const uint2*)&yb[(size_t)s3*NH + q*4];
        acc4(u0, a0,a1,a2,a3); acc4(u1, a0,a1,a2,a3);
        acc4(u2, a0,a1,a2,a3); acc4(u3, a0,a1,a2,a3);
    }
    for (; e < o1; ++e){
        uint2 u = *(const uint2*)&yb[(size_t)csr[e]*NH + q*4];
        acc4(u, a0,a1,a2,a3);
    }
    float dd = (float)(o1 - o0); dd = dd > 1.f ? dd : 1.f;
    float inv = 1.f / dd;
    size_t base = (size_t)node*NH + q*4;
    float4 zz = *(const float4*)&z[base];
    float4 v;
    v.x = a0*inv + zz.x; v.y = a1*inv + zz.y;
    v.z = a2*inv + zz.z; v.w = a3*inv + zz.w;
    v.x = v.x > 0.f ? v.x : 0.f;  v.y = v.y > 0.f ? v.y : 0.f;
    v.z = v.z > 0.f ? v.z : 0.f;  v.w = v.w > 0.f ? v.w : 0.f;
    if (writeBf){
        uint2 u;
        u.x = (unsigned)f2bf(v.x) | ((unsigned)f2bf(v.y) << 16);
        u.y = (unsigned)f2bf(v.z) | ((unsigned)f2bf(v.w) << 16);
        *(uint2*)&outb[base] = u;
    } else {
        *(float4*)&outf[base] = v;
    }
}

// ------ head v3: bitonic-sort top-30 (all 256 threads) + conv + fc1 + fc2 + lsm ----
__global__ __launch_bounds__(256) void head3_kernel(
    const float* __restrict__ h3, const int* __restrict__ starts,
    const float* __restrict__ wT, const float* __restrict__ cbf,
    const float* __restrict__ l1wf, const float* __restrict__ l1bf,
    const float* __restrict__ l2wf, const float* __restrict__ l2bf,
    float* __restrict__ outp)
{
    __shared__ u64  keys[256];
    __shared__ int  sel[KP];
    __shared__ float pT[64*32];          // pT[ch][rank], ranks 30,31 zeroed
    __shared__ float part[8*832];
    __shared__ float cbuf[832];
    __shared__ float fbuf[NH];
    __shared__ float logitsS[NCLS];
    int g = blockIdx.x, tid = threadIdx.x;
    int s = starts[g], e = starts[g+1];
    int cnt = e - s; if (cnt > 256) cnt = 256; if (cnt < 0) cnt = 0;

    u64 key = 0xFFFFFFFFFFFFFFFFull;
    if (tid < cnt){
        float v = h3[(size_t)(s+tid)*NH + 63];
        unsigned u = __float_as_uint(v);
        unsigned m = (u & 0x80000000u) ? ~u : (u | 0x80000000u);
        unsigned d = ~m;
        key = ((u64)d << 32) | (unsigned)tid;
    }
    keys[tid] = key;
    __syncthreads();
    for (int k = 2; k <= 256; k <<= 1){
        for (int j = k >> 1; j > 0; j >>= 1){
            int partner = tid ^ j;
            u64 a = keys[tid], b = keys[partner];
            bool up = ((tid & k) == 0);
            bool amin = a < b;
            u64 keep;
            if (partner > tid) keep = (up == amin) ? a : b;
            else               keep = (up == amin) ? b : a;
            __syncthreads();
            keys[tid] = keep;
            __syncthreads();
        }
    }
    if (tid < KP){
        u64 kk = keys[tid];
        sel[tid] = ((unsigned)(kk >> 32) == 0xFFFFFFFFu) ? -1 : (int)(kk & 0xFFFFFFFFu);
    }
    if (tid < 64){ pT[tid*32 + 30] = 0.f; pT[tid*32 + 31] = 0.f; }
    __syncthreads();
    for (int i = tid; i < KP*64; i += 256){
        int r = i >> 6, f = i & 63;
        int li = sel[r];
        pT[f*32 + r] = (li >= 0) ? h3[(size_t)(s+li)*NH + f] : 0.f;
    }
    __syncthreads();

    int o = tid & 31, chg = tid >> 5;
    float acc[26];
    #pragma unroll
    for (int t = 0; t < 26; ++t) acc[t] = 0.f;
    for (int c8 = 0; c8 < 8; ++c8){
        int ch = chg*8 + c8;
        const float4* prow = (const float4*)&pT[ch*32];
        float p[32];
        #pragma unroll
        for (int q = 0; q < 8; ++q){
            float4 v = prow[q];
            p[4*q]=v.x; p[4*q+1]=v.y; p[4*q+2]=v.z; p[4*q+3]=v.w;
        }
        const float* wrow = &wT[ch*160 + o];
        #pragma unroll
        for (int h = 0; h < 5; ++h){
            float wv = wrow[h*32];
            #pragma unroll
            for (int t = 0; t < 26; ++t) acc[t] += p[t+h]*wv;
        }
    }
    #pragma unroll
    for (int t = 0; t < 26; ++t) part[chg*832 + o*26 + t] = acc[t];
    __syncthreads();

    for (int i = tid; i < 832; i += 256){
        int oo = i / 26;
        float a = cbf[oo];
        #pragma unroll
        for (int cg = 0; cg < 8; ++cg) a += part[cg*832 + i];
        cbuf[i] = a > 0.f ? a : 0.f;
    }
    __syncthreads();

    {   // fc1: 832 -> 64
        int p = tid >> 6, j = tid & 63;
        float a = 0.f;
        int m0 = p*208;
        #pragma unroll 4
        for (int m = m0; m < m0 + 208; ++m)
            a += cbuf[m] * l1wf[(size_t)m*NH + j];
        part[p*NH + j] = a;
    }
    __syncthreads();
    if (tid < NH){
        float v = part[tid] + part[NH+tid] + part[2*NH+tid] + part[3*NH+tid] + l1bf[tid];
        fbuf[tid] = v > 0.f ? v : 0.f;
    }
    __syncthreads();
    if (tid < NCLS){
        float a = l2bf[tid];
        #pragma unroll
        for (int j = 0; j < NH; ++j) a += fbuf[j] * l2wf[j*NCLS + tid];
        logitsS[tid] = a;
    }
    __syncthreads();
    if (tid == 0){
        float m = logitsS[0];
        for (int c = 1; c < NCLS; ++c) m = fmaxf(m, logitsS[c]);
        float ssum = 0.f;
        for (int c = 0; c < NCLS; ++c) ssum += expf(logitsS[c]-m);
        float lse = m + logf(ssum);
        for (int c = 0; c < NCLS; ++c)
            outp[(size_t)g*NCLS + c] = logitsS[c] - lse;
    }
}

extern "C" void kernel_launch(void* const* d_in, const int* in_sizes, int n_in,
                              void* d_out, int out_size, void* d_ws, size_t ws_size,
                              hipStream_t stream) {
    const void* x    = d_in[0];
    const int*  ei   = (const int*)d_in[1];
    const int*  batch= (const int*)d_in[2];
    const void *W1l=d_in[3], *b1=d_in[4],  *W1r=d_in[5];
    const void *W2l=d_in[6], *b2=d_in[7],  *W2r=d_in[8];
    const void *W3l=d_in[9], *b3=d_in[10], *W3r=d_in[11];
    const void *convw=d_in[12], *convb=d_in[13];
    const void *l1w=d_in[14], *l1b=d_in[15];
    const void *l2w=d_in[16], *l2b=d_in[17];
    float* out = (float*)d_out;

    float* wsf = (float*)d_ws;
    ushort_t* ybf = (ushort_t*)wsf;                       // NND*64 bf16 = 6.4MB
    float* z   = wsf + (size_t)NND*NH/2;                  // NND*64 f32 = 12.8MB
    ushort_t* hbf = (ushort_t*)(z + (size_t)NND*NH);      // NND*64 bf16 = 6.4MB
    float* h3  = (float*)(hbf + (size_t)NND*NH);          // NND*64 f32 = 12.8MB
    int2* bedges = (int2*)(h3 + (size_t)NND*NH);          // NE int2 = 6.4MB
    ushort_t* wB1 = (ushort_t*)(bedges + NE);             // 16384
    ushort_t* wB2 = wB1 + 16384;                          // 8192
    ushort_t* wB3 = wB2 + 8192;                           // 8192
    float* b1f  = (float*)(wB3 + 8192);                   // 64
    float* b2f  = b1f + 64;
    float* b3f  = b2f + 64;
    float* wT   = b3f + 64;                               // 10240
    float* cbf  = wT + 10240;                             // 32
    float* l1wf = cbf + 32;                               // 53248
    float* l1bf = l1wf + 53248;                           // 64
    float* l2wf = l1bf + 64;                              // 640
    float* l2bf = l2wf + 640;                             // 10 (+pad)
    int* starts = (int*)(l2bf + 16);                      // 513
    int* flags  = starts + 520;                           // 2
    int* bcnt   = flags + 8;                              // 49
    int* bbase  = bcnt + 64;                              // 50
    int* bcur   = bbase + 64;                             // 49
    int* offs   = bcur + 64;                              // 50001
    int* csr    = offs + NND + 3;                         // 800000

    probe_kernel<<<1, 256, 0, stream>>>((const unsigned int*)x, ei, flags);
    setup_kernel<<<(53248+255)/256, 256, 0, stream>>>(batch, starts,
        W1l, W1r, b1, W2l, W2r, b2, W3l, W3r, b3,
        convw, convb, l1w, l1b, l2w, l2b,
        wB1, wB2, wB3, b1f, b2f, b3f,
        wT, cbf, l1wf, l1bf, l2wf, l2bf, flags);

    // ---- CSR build via bucket sort ----
    const int NTILE = (NE + 4095)/4096;          // 196
    (void)hipMemsetAsync(bcnt, 0, NBKT*sizeof(int), stream);
    bucket_count<<<NTILE, 256, 0, stream>>>(ei, bcnt, flags);
    bucket_scan<<<1, 64, 0, stream>>>(bcnt, bbase, bcur, offs);
    bucket_scatter<<<NTILE, 256, 0, stream>>>(ei, bcur, bedges, flags);
    csr_finalize<<<NBKT, 1024, 0, stream>>>(bedges, bbase, offs, csr);

    int mblocks = (NND + 63)/64;                 // 782
    int ngath   = (NND*16 + 255)/256;            // 3125

    // ---- layer 1: x -> hbf (bf16) ----
    mfma_dualgemm<NF><<<mblocks,256,0,stream>>>(x, wB1, b1f, ybf, z, flags, 0);
    gather_kernel<<<ngath,256,0,stream>>>(ybf, offs, csr, z, nullptr, hbf, 1);

    // ---- layer 2: hbf -> hbf ----
    mfma_dualgemm<NH><<<mblocks,256,0,stream>>>(hbf, wB2, b2f, ybf, z, flags, 1);
    gather_kernel<<<ngath,256,0,stream>>>(ybf, offs, csr, z, nullptr, hbf, 1);

    // ---- layer 3: hbf -> h3 (fp32, head input) ----
    mfma_dualgemm<NH><<<mblocks,256,0,stream>>>(hbf, wB3, b3f, ybf, z, flags, 1);
    gather_kernel<<<ngath,256,0,stream>>>(ybf, offs, csr, z, h3, nullptr, 0);

    // ---- head ----
    head3_kernel<<<NB,256,0,stream>>>(h3, starts, wT, cbf, l1wf, l1bf, l2wf, l2bf, out);
}

// Round 13
// 280.286 us; speedup vs baseline: 1.9240x; 1.0672x over previous
//
#include <hip/hip_runtime.h>
#include <hip/hip_bf16.h>
#include <math.h>

#define NND 50000
#define NE 800000
#define NF 128
#define NH 64
#define NB 512
#define KP 30
#define NCLS 10
#define NBKT 49              // coarse buckets of 1024 dsts

typedef __hip_bfloat16 bf16;
typedef unsigned long long u64;
typedef unsigned short ushort_t;
typedef __attribute__((ext_vector_type(8))) short bf16x8;   // 8 bf16 (4 VGPRs)
typedef __attribute__((ext_vector_type(4))) float f32x4;

__device__ __forceinline__ float ldF(const void* p, size_t i, int isbf){
    return isbf ? __bfloat162float(((const bf16*)p)[i]) : ((const float*)p)[i];
}

// fp32 -> bf16 bits, round-to-nearest-even (matches HW/numpy)
__device__ __forceinline__ ushort_t f2bf(float v){
    unsigned u = __float_as_uint(v);
    unsigned r = u + 0x7FFFu + ((u >> 16) & 1u);
    return (ushort_t)(r >> 16);
}

// ---------------- dtype probe (+ zero bcnt): flags[0]=bf16 floats, flags[1]=int64 ----
__global__ void probe_kernel(const unsigned int* __restrict__ xw,
                             const int* __restrict__ ew, int* __restrict__ flags,
                             int* __restrict__ bcnt){
    __shared__ int cF, cI;
    if (threadIdx.x == 0){ cF = 0; cI = 0; }
    if (threadIdx.x < NBKT) bcnt[threadIdx.x] = 0;
    __syncthreads();
    unsigned int w = xw[threadIdx.x];
    int ex = (int)((w >> 7) & 0xFF);
    if (ex >= 100 && ex <= 140) atomicAdd(&cF, 1);
    if (ew[2*threadIdx.x + 1] == 0) atomicAdd(&cI, 1);
    __syncthreads();
    if (threadIdx.x == 0){
        flags[0] = (cF >= 128) ? 1 : 0;
        flags[1] = (cI >= 192) ? 1 : 0;
    }
}

__device__ __forceinline__ int edgeSrc(const int* ei, int e, int i64){
    return i64 ? ei[2*e] : ei[e];
}
__device__ __forceinline__ int edgeDst(const int* ei, int e, int i64){
    return i64 ? ei[2*NE + 2*e] : ei[NE + e];
}

// ------------- setup: starts + head weights fp32 + MFMA B-frag swizzled weights -----
__global__ __launch_bounds__(256) void setup_kernel(
    const int* __restrict__ batch, int* __restrict__ starts,
    const void* W1l, const void* W1r, const void* b1,
    const void* W2l, const void* W2r, const void* b2,
    const void* W3l, const void* W3r, const void* b3,
    const void* convw, const void* convb,
    const void* l1w, const void* l1b, const void* l2w, const void* l2b,
    ushort_t* __restrict__ wB1, ushort_t* __restrict__ wB2, ushort_t* __restrict__ wB3,
    float* __restrict__ b1f, float* __restrict__ b2f, float* __restrict__ b3f,
    float* __restrict__ wT, float* __restrict__ cbf,
    float* __restrict__ l1wf, float* __restrict__ l1bf,
    float* __restrict__ l2wf, float* __restrict__ l2bf,
    const int* __restrict__ flags)
{
    int wbf = flags[0];
    int i64 = flags[1];
    int i = blockIdx.x*256 + threadIdx.x;
    if (i < NND){
        int b  = i64 ? batch[2*i] : batch[i];
        int pb = (i == 0) ? -1 : (i64 ? batch[2*(i-1)] : batch[i-1]);
        for (int g = pb+1; g <= b; ++g) starts[g] = i;
        if (i == NND-1) for (int g = b+1; g <= NB; ++g) starts[g] = NND;
    }
    // MFMA B-frag swizzle: [c][t][lane][j]; k=c*32+(lane>>4)*8+j, n=t*16+(lane&15)
    {
        int j = i & 7, lane = (i >> 3) & 63, t = (i >> 9) & 7, c = i >> 12;
        int k = c*32 + (lane >> 4)*8 + j;
        int n = t*16 + (lane & 15);
        if (i < 16384){   // layer 1, K=128, KC=4
            float v = (n < 64) ? ldF(W1l, (size_t)k*NH + n, wbf)
                               : ldF(W1r, (size_t)k*NH + (n-64), wbf);
            wB1[i] = f2bf(v);
        }
        if (i < 8192){    // layers 2,3, K=64, KC=2
            float v2 = (n < 64) ? ldF(W2l, (size_t)k*NH + n, wbf)
                                : ldF(W2r, (size_t)k*NH + (n-64), wbf);
            float v3 = (n < 64) ? ldF(W3l, (size_t)k*NH + n, wbf)
                                : ldF(W3r, (size_t)k*NH + (n-64), wbf);
            wB2[i] = f2bf(v2);
            wB3[i] = f2bf(v3);
        }
    }
    if (i < 64){
        b1f[i] = ldF(b1, i, wbf);
        b2f[i] = ldF(b2, i, wbf);
        b3f[i] = ldF(b3, i, wbf);
        l1bf[i] = ldF(l1b, i, wbf);
    }
    if (i < 10240){
        int o = i / 320, rem = i - o*320, ch = rem/5, h = rem - ch*5;
        wT[ch*160 + h*32 + o] = ldF(convw, i, wbf);   // wT[ch][h][o]
    }
    if (i < 53248) l1wf[i] = ldF(l1w, i, wbf);
    if (i < 640)   l2wf[i] = ldF(l2w, i, wbf);
    if (i < 32)    cbf[i]  = ldF(convb, i, wbf);
    if (i < 10)    l2bf[i] = ldF(l2b, i, wbf);
}

// ============ CSR build via 2-level bucket sort (r7, measured good) ============
__global__ __launch_bounds__(256) void bucket_count(const int* __restrict__ ei,
                                                    int* __restrict__ bcnt,
                                                    const int* __restrict__ flags){
    __shared__ int lh[NBKT];
    int tid = threadIdx.x;
    int i64 = flags[1];
    if (tid < NBKT) lh[tid] = 0;
    __syncthreads();
    int t0 = blockIdx.x*4096;
    #pragma unroll 4
    for (int k = 0; k < 16; ++k){
        int e = t0 + k*256 + tid;
        if (e < NE) atomicAdd(&lh[edgeDst(ei,e,i64) >> 10], 1);
    }
    __syncthreads();
    if (tid < NBKT && lh[tid]) atomicAdd(&bcnt[tid], lh[tid]);
}

__global__ void bucket_scan(const int* __restrict__ bcnt, int* __restrict__ bbase,
                            int* __restrict__ bcur, int* __restrict__ offs){
    if (threadIdx.x == 0){
        int acc = 0;
        for (int b = 0; b < NBKT; ++b){
            bbase[b] = acc; bcur[b] = acc; acc += bcnt[b];
        }
        bbase[NBKT] = acc;
        offs[NND] = NE;
    }
}

__global__ __launch_bounds__(256) void bucket_scatter(const int* __restrict__ ei,
                                                      int* __restrict__ bcur,
                                                      int2* __restrict__ bedges,
                                                      const int* __restrict__ flags){
    __shared__ int lh[NBKT];
    __shared__ int lcur[NBKT];
    int tid = threadIdx.x;
    int i64 = flags[1];
    if (tid < NBKT) lh[tid] = 0;
    __syncthreads();
    int t0 = blockIdx.x*4096;
    int myd[16], mys[16];
    int cnt = 0;
    #pragma unroll 4
    for (int k = 0; k < 16; ++k){
        int e = t0 + k*256 + tid;
        if (e < NE){
            int d = edgeDst(ei,e,i64), s_ = edgeSrc(ei,e,i64);
            myd[cnt] = d; mys[cnt] = s_; ++cnt;
            atomicAdd(&lh[d >> 10], 1);
        }
    }
    __syncthreads();
    if (tid < NBKT) lcur[tid] = lh[tid] ? atomicAdd(&bcur[tid], lh[tid]) : 0;
    __syncthreads();
    for (int k = 0; k < cnt; ++k){
        int b = myd[k] >> 10;
        int p = atomicAdd(&lcur[b], 1);
        bedges[p] = make_int2(mys[k], myd[k]);
    }
}

__global__ __launch_bounds__(1024) void csr_finalize(const int2* __restrict__ bedges,
                                                     const int* __restrict__ bbase,
                                                     int* __restrict__ offs,
                                                     int* __restrict__ csr){
    __shared__ int hist[1024];
    int b = blockIdx.x;
    int tid = threadIdx.x;
    int dst0 = b << 10;
    int nd = NND - dst0; if (nd > 1024) nd = 1024;
    int e0 = bbase[b], e1 = bbase[b+1];
    hist[tid] = 0;
    __syncthreads();
    for (int e = e0 + tid; e < e1; e += 1024)
        atomicAdd(&hist[bedges[e].y - dst0], 1);
    __syncthreads();
    int own = hist[tid];
    for (int st = 1; st < 1024; st <<= 1){
        int v = (tid >= st) ? hist[tid-st] : 0;
        __syncthreads();
        hist[tid] += v;
        __syncthreads();
    }
    int excl = hist[tid] - own;
    if (tid < nd) offs[dst0 + tid] = e0 + excl;
    __syncthreads();
    hist[tid] = excl;
    __syncthreads();
    for (int e = e0 + tid; e < e1; e += 1024){
        int2 ed = bedges[e];
        int p = atomicAdd(&hist[ed.y - dst0], 1);
        csr[e0 + p] = ed.x;
    }
}

// ------------- MFMA dual GEMM (layer 1): [y|z] = h @ [Wl|Wr] + [0|b] --------
template<int K>
__global__ __launch_bounds__(256) void mfma_dualgemm(
    const void* __restrict__ in, const ushort_t* __restrict__ wB,
    const float* __restrict__ bfp, ushort_t* __restrict__ ybf,
    float* __restrict__ z, const int* __restrict__ flags, int inIsBf)
{
    constexpr int KC = K/32;
    constexpr int RS = K + 8;                  // LDS row stride (ushorts)
    __shared__ ushort_t hA[64*RS];
    int tid = threadIdx.x;
    int isbf = inIsBf ? 1 : flags[0];
    int base = blockIdx.x * 64;
    for (int i = tid; i < 64*K; i += 256){
        int r = i / K, c = i - r*K;
        int node = base + r;
        float v = (node < NND) ? ldF(in, (size_t)node*K + c, isbf) : 0.f;
        hA[r*RS + c] = f2bf(v);
    }
    __syncthreads();
    int lane = tid & 63, w = tid >> 6;
    int n16 = lane & 15, quad = lane >> 4;
    f32x4 acc[8];
    #pragma unroll
    for (int t = 0; t < 8; ++t) acc[t] = (f32x4){0.f,0.f,0.f,0.f};
    const bf16x8* bp = (const bf16x8*)wB;
    #pragma unroll
    for (int c = 0; c < KC; ++c){
        bf16x8 a = *(const bf16x8*)&hA[(w*16 + n16)*RS + c*32 + quad*8];
        #pragma unroll
        for (int t = 0; t < 8; ++t){
            bf16x8 b = bp[(c*8 + t)*64 + lane];
            acc[t] = __builtin_amdgcn_mfma_f32_16x16x32_bf16(a, b, acc[t], 0, 0, 0);
        }
    }
    #pragma unroll
    for (int t = 0; t < 8; ++t){
        int f = (t & 3)*16 + n16;
        float bv = (t >= 4) ? bfp[f] : 0.f;
        #pragma unroll
        for (int r = 0; r < 4; ++r){
            int node = base + w*16 + quad*4 + r;
            if (node < NND){
                if (t < 4) ybf[(size_t)node*NH + f] = f2bf(acc[t][r]);
                else       z[(size_t)node*NH + f] = acc[t][r] + bv;
            }
        }
    }
}

__device__ __forceinline__ void addbf8(uint4 u, float* a){
    a[0] += __uint_as_float(u.x << 16);
    a[1] += __uint_as_float(u.x & 0xFFFF0000u);
    a[2] += __uint_as_float(u.y << 16);
    a[3] += __uint_as_float(u.y & 0xFFFF0000u);
    a[4] += __uint_as_float(u.z << 16);
    a[5] += __uint_as_float(u.z & 0xFFFF0000u);
    a[6] += __uint_as_float(u.w << 16);
    a[7] += __uint_as_float(u.w & 0xFFFF0000u);
}

// ------ FUSED: h = relu(mean_csr(y)+z) -> LDS A-tile -> MFMA [y'|z'] (layers 2,3) ----
// Phase A: 4 lanes/node, 32B/edge/lane, unroll-4 (8×16B loads in flight).
// h never touches global. Phase B: identical MFMA body, K=64.
__global__ __launch_bounds__(256) void gather_mfma(
    const ushort_t* __restrict__ yb, const int* __restrict__ offs,
    const int* __restrict__ csr, const float* __restrict__ z,
    const ushort_t* __restrict__ wB, const float* __restrict__ bfp,
    ushort_t* __restrict__ ybf_out, float* __restrict__ z_out)
{
    constexpr int K = NH;                      // 64
    constexpr int KC = K/32;                   // 2
    constexpr int RS = K + 8;                  // 72 ushorts
    __shared__ ushort_t hA[64*RS];
    int tid = threadIdx.x;
    int base = blockIdx.x * 64;

    // ---- phase A: gather+finalize 64 nodes into hA ----
    {
        int nl = tid >> 2, q = tid & 3;        // node-local row, 16-feat chunk
        int node = base + nl;
        float acc[16];
        #pragma unroll
        for (int i = 0; i < 16; ++i) acc[i] = 0.f;
        ushort_t row[16];
        if (node < NND){
            int o0 = offs[node], o1 = offs[node+1];
            int e = o0;
            for (; e + 3 < o1; e += 4){
                int s0 = csr[e], s1 = csr[e+1], s2 = csr[e+2], s3 = csr[e+3];
                const uint4* p0 = (const uint4*)&yb[(size_t)s0*NH + q*16];
                const uint4* p1 = (const uint4*)&yb[(size_t)s1*NH + q*16];
                const uint4* p2 = (const uint4*)&yb[(size_t)s2*NH + q*16];
                const uint4* p3 = (const uint4*)&yb[(size_t)s3*NH + q*16];
                uint4 a0 = p0[0], a1 = p0[1], b0 = p1[0], b1 = p1[1];
                uint4 c0 = p2[0], c1 = p2[1], d0 = p3[0], d1 = p3[1];
                addbf8(a0, acc); addbf8(a1, acc+8);
                addbf8(b0, acc); addbf8(b1, acc+8);
                addbf8(c0, acc); addbf8(c1, acc+8);
                addbf8(d0, acc); addbf8(d1, acc+8);
            }
            for (; e < o1; ++e){
                const uint4* p0 = (const uint4*)&yb[(size_t)csr[e]*NH + q*16];
                uint4 a0 = p0[0], a1 = p0[1];
                addbf8(a0, acc); addbf8(a1, acc+8);
            }
            float dd = (float)(o1 - o0); dd = dd > 1.f ? dd : 1.f;
            float inv = 1.f / dd;
            const float4* zp = (const float4*)&z[(size_t)node*NH + q*16];
            #pragma unroll
            for (int i4 = 0; i4 < 4; ++i4){
                float4 zz = zp[i4];
                float v0 = acc[i4*4+0]*inv + zz.x;
                float v1 = acc[i4*4+1]*inv + zz.y;
                float v2 = acc[i4*4+2]*inv + zz.z;
                float v3 = acc[i4*4+3]*inv + zz.w;
                row[i4*4+0] = f2bf(v0 > 0.f ? v0 : 0.f);
                row[i4*4+1] = f2bf(v1 > 0.f ? v1 : 0.f);
                row[i4*4+2] = f2bf(v2 > 0.f ? v2 : 0.f);
                row[i4*4+3] = f2bf(v3 > 0.f ? v3 : 0.f);
            }
        } else {
            #pragma unroll
            for (int i = 0; i < 16; ++i) row[i] = 0;
        }
        unsigned pk[8];
        #pragma unroll
        for (int i = 0; i < 8; ++i)
            pk[i] = (unsigned)row[2*i] | ((unsigned)row[2*i+1] << 16);
        *(uint4*)&hA[nl*RS + q*16]     = make_uint4(pk[0],pk[1],pk[2],pk[3]);
        *(uint4*)&hA[nl*RS + q*16 + 8] = make_uint4(pk[4],pk[5],pk[6],pk[7]);
    }
    __syncthreads();

    // ---- phase B: MFMA [y'|z'] = hA @ [Wl|Wr] ----
    int lane = tid & 63, w = tid >> 6;
    int n16 = lane & 15, quad = lane >> 4;
    f32x4 acc[8];
    #pragma unroll
    for (int t = 0; t < 8; ++t) acc[t] = (f32x4){0.f,0.f,0.f,0.f};
    const bf16x8* bp = (const bf16x8*)wB;
    #pragma unroll
    for (int c = 0; c < KC; ++c){
        bf16x8 a = *(const bf16x8*)&hA[(w*16 + n16)*RS + c*32 + quad*8];
        #pragma unroll
        for (int t = 0; t < 8; ++t){
            bf16x8 b = bp[(c*8 + t)*64 + lane];
            acc[t] = __builtin_amdgcn_mfma_f32_16x16x32_bf16(a, b, acc[t], 0, 0, 0);
        }
    }
    #pragma unroll
    for (int t = 0; t < 8; ++t){
        int f = (t & 3)*16 + n16;
        float bv = (t >= 4) ? bfp[f] : 0.f;
        #pragma unroll
        for (int r = 0; r < 4; ++r){
            int node = base + w*16 + quad*4 + r;
            if (node < NND){
                if (t < 4) ybf_out[(size_t)node*NH + f] = f2bf(acc[t][r]);
                else       z_out[(size_t)node*NH + f] = acc[t][r] + bv;
            }
        }
    }
}

// ---------------- final gather: h3(fp32) = relu(mean_csr(y) + z) ------
__device__ __forceinline__ void acc4(uint2 u, float& a0, float& a1, float& a2, float& a3){
    a0 += __uint_as_float(u.x << 16);
    a1 += __uint_as_float(u.x & 0xFFFF0000u);
    a2 += __uint_as_float(u.y << 16);
    a3 += __uint_as_float(u.y & 0xFFFF0000u);
}

__global__ __launch_bounds__(256) void gather_kernel(
    const ushort_t* __restrict__ yb, const int* __restrict__ offs,
    const int* __restrict__ csr, const float* __restrict__ z,
    float* __restrict__ outf)
{
    int t = blockIdx.x*256 + threadIdx.x;
    int node = t >> 4;
    int q = t & 15;
    if (node >= NND) return;
    int o0 = offs[node], o1 = offs[node+1];
    float a0=0.f, a1=0.f, a2=0.f, a3=0.f;
    int e = o0;
    for (; e + 3 < o1; e += 4){
        int s0 = csr[e], s1 = csr[e+1], s2 = csr[e+2], s3 = csr[e+3];
        uint2 u0 = *(const uint2*)&yb[(size_t)s0*NH + q*4];
        uint2 u1 = *(const uint2*)&yb[(size_t)s1*NH + q*4];
        uint2 u2 = *(const uint2*)&yb[(size_t)s2*NH + q*4];
        uint2 u3 = *(const uint2*)&yb[(size_t)s3*NH + q*4];
        acc4(u0, a0,a1,a2,a3); acc4(u1, a0,a1,a2,a3);
        acc4(u2, a0,a1,a2,a3); acc4(u3, a0,a1,a2,a3);
    }
    for (; e < o1; ++e){
        uint2 u = *(const uint2*)&yb[(size_t)csr[e]*NH + q*4];
        acc4(u, a0,a1,a2,a3);
    }
    float dd = (float)(o1 - o0); dd = dd > 1.f ? dd : 1.f;
    float inv = 1.f / dd;
    size_t base = (size_t)node*NH + q*4;
    float4 zz = *(const float4*)&z[base];
    float4 v;
    v.x = a0*inv + zz.x; v.y = a1*inv + zz.y;
    v.z = a2*inv + zz.z; v.w = a3*inv + zz.w;
    v.x = v.x > 0.f ? v.x : 0.f;  v.y = v.y > 0.f ? v.y : 0.f;
    v.z = v.z > 0.f ? v.z : 0.f;  v.w = v.w > 0.f ? v.w : 0.f;
    *(float4*)&outf[base] = v;
}

// ------ head v3: bitonic-sort top-30 (all 256 threads) + conv + fc1 + fc2 + lsm ----
__global__ __launch_bounds__(256) void head3_kernel(
    const float* __restrict__ h3, const int* __restrict__ starts,
    const float* __restrict__ wT, const float* __restrict__ cbf,
    const float* __restrict__ l1wf, const float* __restrict__ l1bf,
    const float* __restrict__ l2wf, const float* __restrict__ l2bf,
    float* __restrict__ outp)
{
    __shared__ u64  keys[256];
    __shared__ int  sel[KP];
    __shared__ float pT[64*32];          // pT[ch][rank], ranks 30,31 zeroed
    __shared__ float part[8*832];
    __shared__ float cbuf[832];
    __shared__ float fbuf[NH];
    __shared__ float logitsS[NCLS];
    int g = blockIdx.x, tid = threadIdx.x;
    int s = starts[g], e = starts[g+1];
    int cnt = e - s; if (cnt > 256) cnt = 256; if (cnt < 0) cnt = 0;

    u64 key = 0xFFFFFFFFFFFFFFFFull;
    if (tid < cnt){
        float v = h3[(size_t)(s+tid)*NH + 63];
        unsigned u = __float_as_uint(v);
        unsigned m = (u & 0x80000000u) ? ~u : (u | 0x80000000u);
        unsigned d = ~m;
        key = ((u64)d << 32) | (unsigned)tid;
    }
    keys[tid] = key;
    __syncthreads();
    for (int k = 2; k <= 256; k <<= 1){
        for (int j = k >> 1; j > 0; j >>= 1){
            int partner = tid ^ j;
            u64 a = keys[tid], b = keys[partner];
            bool up = ((tid & k) == 0);
            bool amin = a < b;
            u64 keep;
            if (partner > tid) keep = (up == amin) ? a : b;
            else               keep = (up == amin) ? b : a;
            __syncthreads();
            keys[tid] = keep;
            __syncthreads();
        }
    }
    if (tid < KP){
        u64 kk = keys[tid];
        sel[tid] = ((unsigned)(kk >> 32) == 0xFFFFFFFFu) ? -1 : (int)(kk & 0xFFFFFFFFu);
    }
    if (tid < 64){ pT[tid*32 + 30] = 0.f; pT[tid*32 + 31] = 0.f; }
    __syncthreads();
    for (int i = tid; i < KP*64; i += 256){
        int r = i >> 6, f = i & 63;
        int li = sel[r];
        pT[f*32 + r] = (li >= 0) ? h3[(size_t)(s+li)*NH + f] : 0.f;
    }
    __syncthreads();

    int o = tid & 31, chg = tid >> 5;
    float acc[26];
    #pragma unroll
    for (int t = 0; t < 26; ++t) acc[t] = 0.f;
    for (int c8 = 0; c8 < 8; ++c8){
        int ch = chg*8 + c8;
        const float4* prow = (const float4*)&pT[ch*32];
        float p[32];
        #pragma unroll
        for (int q = 0; q < 8; ++q){
            float4 v = prow[q];
            p[4*q]=v.x; p[4*q+1]=v.y; p[4*q+2]=v.z; p[4*q+3]=v.w;
        }
        const float* wrow = &wT[ch*160 + o];
        #pragma unroll
        for (int h = 0; h < 5; ++h){
            float wv = wrow[h*32];
            #pragma unroll
            for (int t = 0; t < 26; ++t) acc[t] += p[t+h]*wv;
        }
    }
    #pragma unroll
    for (int t = 0; t < 26; ++t) part[chg*832 + o*26 + t] = acc[t];
    __syncthreads();

    for (int i = tid; i < 832; i += 256){
        int oo = i / 26;
        float a = cbf[oo];
        #pragma unroll
        for (int cg = 0; cg < 8; ++cg) a += part[cg*832 + i];
        cbuf[i] = a > 0.f ? a : 0.f;
    }
    __syncthreads();

    {   // fc1: 832 -> 64
        int p = tid >> 6, j = tid & 63;
        float a = 0.f;
        int m0 = p*208;
        #pragma unroll 4
        for (int m = m0; m < m0 + 208; ++m)
            a += cbuf[m] * l1wf[(size_t)m*NH + j];
        part[p*NH + j] = a;
    }
    __syncthreads();
    if (tid < NH){
        float v = part[tid] + part[NH+tid] + part[2*NH+tid] + part[3*NH+tid] + l1bf[tid];
        fbuf[tid] = v > 0.f ? v : 0.f;
    }
    __syncthreads();
    if (tid < NCLS){
        float a = l2bf[tid];
        #pragma unroll
        for (int j = 0; j < NH; ++j) a += fbuf[j] * l2wf[j*NCLS + tid];
        logitsS[tid] = a;
    }
    __syncthreads();
    if (tid == 0){
        float m = logitsS[0];
        for (int c = 1; c < NCLS; ++c) m = fmaxf(m, logitsS[c]);
        float ssum = 0.f;
        for (int c = 0; c < NCLS; ++c) ssum += expf(logitsS[c]-m);
        float lse = m + logf(ssum);
        for (int c = 0; c < NCLS; ++c)
            outp[(size_t)g*NCLS + c] = logitsS[c] - lse;
    }
}

extern "C" void kernel_launch(void* const* d_in, const int* in_sizes, int n_in,
                              void* d_out, int out_size, void* d_ws, size_t ws_size,
                              hipStream_t stream) {
    const void* x    = d_in[0];
    const int*  ei   = (const int*)d_in[1];
    const int*  batch= (const int*)d_in[2];
    const void *W1l=d_in[3], *b1=d_in[4],  *W1r=d_in[5];
    const void *W2l=d_in[6], *b2=d_in[7],  *W2r=d_in[8];
    const void *W3l=d_in[9], *b3=d_in[10], *W3r=d_in[11];
    const void *convw=d_in[12], *convb=d_in[13];
    const void *l1w=d_in[14], *l1b=d_in[15];
    const void *l2w=d_in[16], *l2b=d_in[17];
    float* out = (float*)d_out;

    float* wsf = (float*)d_ws;
    ushort_t* yA = (ushort_t*)wsf;                        // NND*64 bf16
    float* zA  = wsf + (size_t)NND*NH/2;                  // NND*64 f32
    ushort_t* yB = (ushort_t*)(zA + (size_t)NND*NH);      // NND*64 bf16
    float* zB  = (float*)(yB + (size_t)NND*NH);           // NND*64 f32
    float* h3  = zB + (size_t)NND*NH;                     // NND*64 f32
    int2* bedges = (int2*)(h3 + (size_t)NND*NH);          // NE int2
    ushort_t* wB1 = (ushort_t*)(bedges + NE);             // 16384
    ushort_t* wB2 = wB1 + 16384;                          // 8192
    ushort_t* wB3 = wB2 + 8192;                           // 8192
    float* b1f  = (float*)(wB3 + 8192);                   // 64
    float* b2f  = b1f + 64;
    float* b3f  = b2f + 64;
    float* wT   = b3f + 64;                               // 10240
    float* cbf  = wT + 10240;                             // 32
    float* l1wf = cbf + 32;                               // 53248
    float* l1bf = l1wf + 53248;                           // 64
    float* l2wf = l1bf + 64;                              // 640
    float* l2bf = l2wf + 640;                             // 10 (+pad)
    int* starts = (int*)(l2bf + 16);                      // 513
    int* flags  = starts + 520;                           // 2
    int* bcnt   = flags + 8;                              // 49
    int* bbase  = bcnt + 64;                              // 50
    int* bcur   = bbase + 64;                             // 49
    int* offs   = bcur + 64;                              // 50001
    int* csr    = offs + NND + 3;                         // 800000

    probe_kernel<<<1, 256, 0, stream>>>((const unsigned int*)x, ei, flags, bcnt);
    setup_kernel<<<(53248+255)/256, 256, 0, stream>>>(batch, starts,
        W1l, W1r, b1, W2l, W2r, b2, W3l, W3r, b3,
        convw, convb, l1w, l1b, l2w, l2b,
        wB1, wB2, wB3, b1f, b2f, b3f,
        wT, cbf, l1wf, l1bf, l2wf, l2bf, flags);

    // ---- CSR build via bucket sort ----
    const int NTILE = (NE + 4095)/4096;          // 196
    bucket_count<<<NTILE, 256, 0, stream>>>(ei, bcnt, flags);
    bucket_scan<<<1, 64, 0, stream>>>(bcnt, bbase, bcur, offs);
    bucket_scatter<<<NTILE, 256, 0, stream>>>(ei, bcur, bedges, flags);
    csr_finalize<<<NBKT, 1024, 0, stream>>>(bedges, bbase, offs, csr);

    int mblocks = (NND + 63)/64;                 // 782
    int ngath   = (NND*16 + 255)/256;            // 3125

    // ---- layer 1: x -> yA,zA ----
    mfma_dualgemm<NF><<<mblocks,256,0,stream>>>(x, wB1, b1f, yA, zA, flags, 0);
    // ---- fused gather(1)+GEMM(2): yA,zA -> yB,zB ----
    gather_mfma<<<mblocks,256,0,stream>>>(yA, offs, csr, zA, wB2, b2f, yB, zB);
    // ---- fused gather(2)+GEMM(3): yB,zB -> yA,zA ----
    gather_mfma<<<mblocks,256,0,stream>>>(yB, offs, csr, zB, wB3, b3f, yA, zA);
    // ---- final gather: yA,zA -> h3 (fp32) ----
    gather_kernel<<<ngath,256,0,stream>>>(yA, offs, csr, zA, h3);

    // ---- head ----
    head3_kernel<<<NB,256,0,stream>>>(h3, starts, wT, cbf, l1wf, l1bf, l2wf, l2bf, out);
}

// Round 14
// 268.639 us; speedup vs baseline: 2.0074x; 1.0434x over previous
//
#include <hip/hip_runtime.h>
#include <hip/hip_bf16.h>
#include <math.h>

#define NND 50000
#define NE 800000
#define NF 128
#define NH 64
#define NB 512
#define KP 30
#define NCLS 10
#define NBKT 49              // coarse buckets of 1024 dsts
#define NTILE 196            // edge tiles of 4096
#define NG1 782              // layer-1 GEMM blocks (64 nodes each)
#define NSET 208             // setup blocks (208*256 = 53248)

typedef __hip_bfloat16 bf16;
typedef unsigned long long u64;
typedef unsigned short ushort_t;
typedef __attribute__((ext_vector_type(8))) short bf16x8;   // 8 bf16 (4 VGPRs)
typedef __attribute__((ext_vector_type(4))) float f32x4;

__device__ __forceinline__ float ldF(const void* p, size_t i, int isbf){
    return isbf ? __bfloat162float(((const bf16*)p)[i]) : ((const float*)p)[i];
}

// fp32 -> bf16 bits, round-to-nearest-even (matches HW/numpy)
__device__ __forceinline__ ushort_t f2bf(float v){
    unsigned u = __float_as_uint(v);
    unsigned r = u + 0x7FFFu + ((u >> 16) & 1u);
    return (ushort_t)(r >> 16);
}

// ---- wave-uniform dtype detection (no LDS, no barriers; all lanes must be active) ----
__device__ __forceinline__ int floatsAreBf16(const unsigned* __restrict__ xw, int tid){
    unsigned w = xw[tid & 63];
    int ex = (int)((w >> 7) & 0xFF);
    u64 m = __ballot(ex >= 100 && ex <= 140);   // low-half bf16 exponent sanity
    return __popcll(m) >= 32;
}
__device__ __forceinline__ int intsAreI64(const int* __restrict__ ew, int tid){
    u64 m = __ballot(ew[2*(tid & 63) + 1] == 0); // LE int64 -> odd words zero
    return __popcll(m) >= 48;
}

__device__ __forceinline__ int edgeSrc(const int* ei, int e, int i64){
    return i64 ? ei[2*e] : ei[e];
}
__device__ __forceinline__ int edgeDst(const int* ei, int e, int i64){
    return i64 ? ei[2*NE + 2*e] : ei[NE + e];
}

// ========== K1: bucket_count(+last-block scan fold) || setup ==========
__global__ __launch_bounds__(256) void k1_kernel(
    const unsigned* __restrict__ xw, const int* __restrict__ ei,
    const int* __restrict__ batch, int* __restrict__ starts,
    const void* W1l, const void* W1r, const void* b1,
    const void* W2l, const void* W2r, const void* b2,
    const void* W3l, const void* W3r, const void* b3,
    const void* convw, const void* convb,
    const void* l1w, const void* l1b, const void* l2w, const void* l2b,
    ushort_t* __restrict__ wB1, ushort_t* __restrict__ wB2, ushort_t* __restrict__ wB3,
    float* __restrict__ b1f, float* __restrict__ b2f, float* __restrict__ b3f,
    float* __restrict__ wT, float* __restrict__ cbf,
    float* __restrict__ l1wf, float* __restrict__ l1bf,
    float* __restrict__ l2wf, float* __restrict__ l2bf,
    int* __restrict__ bcnt, int* __restrict__ dctr,
    int* __restrict__ bbase, int* __restrict__ bcur, int* __restrict__ offs)
{
    int tid = threadIdx.x;
    if (blockIdx.x < NTILE){
        // ---- bucket count ----
        __shared__ int lh[NBKT];
        __shared__ int sc[NBKT];
        __shared__ int lastFlag;
        int i64 = intsAreI64(ei, tid);
        if (tid < NBKT) lh[tid] = 0;
        __syncthreads();
        int t0 = blockIdx.x*4096;
        #pragma unroll 4
        for (int k = 0; k < 16; ++k){
            int e = t0 + k*256 + tid;
            if (e < NE) atomicAdd(&lh[edgeDst(ei,e,i64) >> 10], 1);
        }
        __syncthreads();
        if (tid < NBKT && lh[tid]) atomicAdd(&bcnt[tid], lh[tid]);
        __syncthreads();
        if (tid == 0){
            __threadfence();
            int old = atomicAdd(dctr, 1);
            lastFlag = (old == NTILE-1) ? 1 : 0;
        }
        __syncthreads();
        if (lastFlag){
            if (tid < NBKT) sc[tid] = atomicAdd(&bcnt[tid], 0);   // atomic read
            __syncthreads();
            if (tid == 0){
                int acc = 0;
                for (int b = 0; b < NBKT; ++b){
                    bbase[b] = acc; bcur[b] = acc; acc += sc[b];
                }
                bbase[NBKT] = acc;
                offs[NND] = NE;
            }
        }
    } else {
        // ---- setup: starts + weight preconvert + MFMA B-frag swizzle ----
        int wbf = floatsAreBf16(xw, tid);
        int i64 = intsAreI64(ei, tid);
        int i = (blockIdx.x - NTILE)*256 + tid;
        if (i < NND){
            int b  = i64 ? batch[2*i] : batch[i];
            int pb = (i == 0) ? -1 : (i64 ? batch[2*(i-1)] : batch[i-1]);
            for (int g = pb+1; g <= b; ++g) starts[g] = i;
            if (i == NND-1) for (int g = b+1; g <= NB; ++g) starts[g] = NND;
        }
        // B-frag swizzle: [c][t][lane][j]; k=c*32+(lane>>4)*8+j, n=t*16+(lane&15)
        {
            int j = i & 7, lane = (i >> 3) & 63, t = (i >> 9) & 7, c = i >> 12;
            int k = c*32 + (lane >> 4)*8 + j;
            int n = t*16 + (lane & 15);
            if (i < 16384){
                float v = (n < 64) ? ldF(W1l, (size_t)k*NH + n, wbf)
                                   : ldF(W1r, (size_t)k*NH + (n-64), wbf);
                wB1[i] = f2bf(v);
            }
            if (i < 8192){
                float v2 = (n < 64) ? ldF(W2l, (size_t)k*NH + n, wbf)
                                    : ldF(W2r, (size_t)k*NH + (n-64), wbf);
                float v3 = (n < 64) ? ldF(W3l, (size_t)k*NH + n, wbf)
                                    : ldF(W3r, (size_t)k*NH + (n-64), wbf);
                wB2[i] = f2bf(v2);
                wB3[i] = f2bf(v3);
            }
        }
        if (i < 64){
            b1f[i] = ldF(b1, i, wbf);
            b2f[i] = ldF(b2, i, wbf);
            b3f[i] = ldF(b3, i, wbf);
            l1bf[i] = ldF(l1b, i, wbf);
        }
        if (i < 10240){
            int o = i / 320, rem = i - o*320, ch = rem/5, h = rem - ch*5;
            wT[ch*160 + h*32 + o] = ldF(convw, i, wbf);   // wT[ch][h][o]
        }
        if (i < 53248) l1wf[i] = ldF(l1w, i, wbf);
        if (i < 640)   l2wf[i] = ldF(l2w, i, wbf);
        if (i < 32)    cbf[i]  = ldF(convb, i, wbf);
        if (i < 10)    l2bf[i] = ldF(l2b, i, wbf);
    }
}

// ========== K2: layer-1 MFMA GEMM || bucket_scatter (independent) ==========
__global__ __launch_bounds__(256) void k2_kernel(
    const void* __restrict__ x, const int* __restrict__ ei,
    const ushort_t* __restrict__ wB1, const float* __restrict__ b1f,
    ushort_t* __restrict__ ybf, float* __restrict__ z,
    int* __restrict__ bcur, int2* __restrict__ bedges)
{
    int tid = threadIdx.x;
    if (blockIdx.x < NG1){
        // ---- L1 GEMM: [y|z] = x @ [W1l|W1r] + [0|b1], K=128 ----
        constexpr int K = NF, KC = K/32, RS = K + 8;
        __shared__ ushort_t hA[64*RS];
        int isbf = floatsAreBf16((const unsigned*)x, tid);
        int base = blockIdx.x * 64;
        for (int i = tid; i < 64*K; i += 256){
            int r = i / K, c = i - r*K;
            int node = base + r;
            float v = (node < NND) ? ldF(x, (size_t)node*K + c, isbf) : 0.f;
            hA[r*RS + c] = f2bf(v);
        }
        __syncthreads();
        int lane = tid & 63, w = tid >> 6;
        int n16 = lane & 15, quad = lane >> 4;
        f32x4 acc[8];
        #pragma unroll
        for (int t = 0; t < 8; ++t) acc[t] = (f32x4){0.f,0.f,0.f,0.f};
        const bf16x8* bp = (const bf16x8*)wB1;
        #pragma unroll
        for (int c = 0; c < KC; ++c){
            bf16x8 a = *(const bf16x8*)&hA[(w*16 + n16)*RS + c*32 + quad*8];
            #pragma unroll
            for (int t = 0; t < 8; ++t){
                bf16x8 b = bp[(c*8 + t)*64 + lane];
                acc[t] = __builtin_amdgcn_mfma_f32_16x16x32_bf16(a, b, acc[t], 0, 0, 0);
            }
        }
        #pragma unroll
        for (int t = 0; t < 8; ++t){
            int f = (t & 3)*16 + n16;
            float bv = (t >= 4) ? b1f[f] : 0.f;
            #pragma unroll
            for (int r = 0; r < 4; ++r){
                int node = base + w*16 + quad*4 + r;
                if (node < NND){
                    if (t < 4) ybf[(size_t)node*NH + f] = f2bf(acc[t][r]);
                    else       z[(size_t)node*NH + f] = acc[t][r] + bv;
                }
            }
        }
    } else {
        // ---- bucket scatter ----
        __shared__ int lh[NBKT];
        __shared__ int lcur[NBKT];
        int i64 = intsAreI64(ei, tid);
        if (tid < NBKT) lh[tid] = 0;
        __syncthreads();
        int t0 = (blockIdx.x - NG1)*4096;
        int myd[16], mys[16];
        int cnt = 0;
        #pragma unroll 4
        for (int k = 0; k < 16; ++k){
            int e = t0 + k*256 + tid;
            if (e < NE){
                int d = edgeDst(ei,e,i64), s_ = edgeSrc(ei,e,i64);
                myd[cnt] = d; mys[cnt] = s_; ++cnt;
                atomicAdd(&lh[d >> 10], 1);
            }
        }
        __syncthreads();
        if (tid < NBKT) lcur[tid] = lh[tid] ? atomicAdd(&bcur[tid], lh[tid]) : 0;
        __syncthreads();
        for (int k = 0; k < cnt; ++k){
            int b = myd[k] >> 10;
            int p = atomicAdd(&lcur[b], 1);
            bedges[p] = make_int2(mys[k], myd[k]);
        }
    }
}

__global__ __launch_bounds__(1024) void csr_finalize(const int2* __restrict__ bedges,
                                                     const int* __restrict__ bbase,
                                                     int* __restrict__ offs,
                                                     int* __restrict__ csr){
    __shared__ int hist[1024];
    int b = blockIdx.x;
    int tid = threadIdx.x;
    int dst0 = b << 10;
    int nd = NND - dst0; if (nd > 1024) nd = 1024;
    int e0 = bbase[b], e1 = bbase[b+1];
    hist[tid] = 0;
    __syncthreads();
    for (int e = e0 + tid; e < e1; e += 1024)
        atomicAdd(&hist[bedges[e].y - dst0], 1);
    __syncthreads();
    int own = hist[tid];
    for (int st = 1; st < 1024; st <<= 1){
        int v = (tid >= st) ? hist[tid-st] : 0;
        __syncthreads();
        hist[tid] += v;
        __syncthreads();
    }
    int excl = hist[tid] - own;
    if (tid < nd) offs[dst0 + tid] = e0 + excl;
    __syncthreads();
    hist[tid] = excl;
    __syncthreads();
    for (int e = e0 + tid; e < e1; e += 1024){
        int2 ed = bedges[e];
        int p = atomicAdd(&hist[ed.y - dst0], 1);
        csr[e0 + p] = ed.x;
    }
}

__device__ __forceinline__ void addbf8(uint4 u, float* a){
    a[0] += __uint_as_float(u.x << 16);
    a[1] += __uint_as_float(u.x & 0xFFFF0000u);
    a[2] += __uint_as_float(u.y << 16);
    a[3] += __uint_as_float(u.y & 0xFFFF0000u);
    a[4] += __uint_as_float(u.z << 16);
    a[5] += __uint_as_float(u.z & 0xFFFF0000u);
    a[6] += __uint_as_float(u.w << 16);
    a[7] += __uint_as_float(u.w & 0xFFFF0000u);
}

// ------ FUSED: h = relu(mean_csr(y)+z) -> LDS A-tile -> MFMA [y'|z'] (layers 2,3) ----
__global__ __launch_bounds__(256) void gather_mfma(
    const ushort_t* __restrict__ yb, const int* __restrict__ offs,
    const int* __restrict__ csr, const float* __restrict__ z,
    const ushort_t* __restrict__ wB, const float* __restrict__ bfp,
    ushort_t* __restrict__ ybf_out, float* __restrict__ z_out)
{
    constexpr int K = NH;
    constexpr int KC = K/32;
    constexpr int RS = K + 8;
    __shared__ ushort_t hA[64*RS];
    int tid = threadIdx.x;
    int base = blockIdx.x * 64;

    {   // phase A: gather+finalize 64 nodes into hA
        int nl = tid >> 2, q = tid & 3;
        int node = base + nl;
        float acc[16];
        #pragma unroll
        for (int i = 0; i < 16; ++i) acc[i] = 0.f;
        ushort_t row[16];
        if (node < NND){
            int o0 = offs[node], o1 = offs[node+1];
            int e = o0;
            for (; e + 3 < o1; e += 4){
                int s0 = csr[e], s1 = csr[e+1], s2 = csr[e+2], s3 = csr[e+3];
                const uint4* p0 = (const uint4*)&yb[(size_t)s0*NH + q*16];
                const uint4* p1 = (const uint4*)&yb[(size_t)s1*NH + q*16];
                const uint4* p2 = (const uint4*)&yb[(size_t)s2*NH + q*16];
                const uint4* p3 = (const uint4*)&yb[(size_t)s3*NH + q*16];
                uint4 a0 = p0[0], a1 = p0[1], b0 = p1[0], b1 = p1[1];
                uint4 c0 = p2[0], c1 = p2[1], d0 = p3[0], d1 = p3[1];
                addbf8(a0, acc); addbf8(a1, acc+8);
                addbf8(b0, acc); addbf8(b1, acc+8);
                addbf8(c0, acc); addbf8(c1, acc+8);
                addbf8(d0, acc); addbf8(d1, acc+8);
            }
            for (; e < o1; ++e){
                const uint4* p0 = (const uint4*)&yb[(size_t)csr[e]*NH + q*16];
                uint4 a0 = p0[0], a1 = p0[1];
                addbf8(a0, acc); addbf8(a1, acc+8);
            }
            float dd = (float)(o1 - o0); dd = dd > 1.f ? dd : 1.f;
            float inv = 1.f / dd;
            const float4* zp = (const float4*)&z[(size_t)node*NH + q*16];
            #pragma unroll
            for (int i4 = 0; i4 < 4; ++i4){
                float4 zz = zp[i4];
                float v0 = acc[i4*4+0]*inv + zz.x;
                float v1 = acc[i4*4+1]*inv + zz.y;
                float v2 = acc[i4*4+2]*inv + zz.z;
                float v3 = acc[i4*4+3]*inv + zz.w;
                row[i4*4+0] = f2bf(v0 > 0.f ? v0 : 0.f);
                row[i4*4+1] = f2bf(v1 > 0.f ? v1 : 0.f);
                row[i4*4+2] = f2bf(v2 > 0.f ? v2 : 0.f);
                row[i4*4+3] = f2bf(v3 > 0.f ? v3 : 0.f);
            }
        } else {
            #pragma unroll
            for (int i = 0; i < 16; ++i) row[i] = 0;
        }
        unsigned pk[8];
        #pragma unroll
        for (int i = 0; i < 8; ++i)
            pk[i] = (unsigned)row[2*i] | ((unsigned)row[2*i+1] << 16);
        *(uint4*)&hA[nl*RS + q*16]     = make_uint4(pk[0],pk[1],pk[2],pk[3]);
        *(uint4*)&hA[nl*RS + q*16 + 8] = make_uint4(pk[4],pk[5],pk[6],pk[7]);
    }
    __syncthreads();

    int lane = tid & 63, w = tid >> 6;
    int n16 = lane & 15, quad = lane >> 4;
    f32x4 acc[8];
    #pragma unroll
    for (int t = 0; t < 8; ++t) acc[t] = (f32x4){0.f,0.f,0.f,0.f};
    const bf16x8* bp = (const bf16x8*)wB;
    #pragma unroll
    for (int c = 0; c < KC; ++c){
        bf16x8 a = *(const bf16x8*)&hA[(w*16 + n16)*RS + c*32 + quad*8];
        #pragma unroll
        for (int t = 0; t < 8; ++t){
            bf16x8 b = bp[(c*8 + t)*64 + lane];
            acc[t] = __builtin_amdgcn_mfma_f32_16x16x32_bf16(a, b, acc[t], 0, 0, 0);
        }
    }
    #pragma unroll
    for (int t = 0; t < 8; ++t){
        int f = (t & 3)*16 + n16;
        float bv = (t >= 4) ? bfp[f] : 0.f;
        #pragma unroll
        for (int r = 0; r < 4; ++r){
            int node = base + w*16 + quad*4 + r;
            if (node < NND){
                if (t < 4) ybf_out[(size_t)node*NH + f] = f2bf(acc[t][r]);
                else       z_out[(size_t)node*NH + f] = acc[t][r] + bv;
            }
        }
    }
}

__device__ __forceinline__ void acc4(uint2 u, float& a0, float& a1, float& a2, float& a3){
    a0 += __uint_as_float(u.x << 16);
    a1 += __uint_as_float(u.x & 0xFFFF0000u);
    a2 += __uint_as_float(u.y << 16);
    a3 += __uint_as_float(u.y & 0xFFFF0000u);
}

// ====== head v4: per-graph key gather (ch63 only) + bitonic top-30 +
//        winner-row re-gather straight into pT + conv + fc1 + fc2 + log_softmax ======
__global__ __launch_bounds__(256) void head4_kernel(
    const ushort_t* __restrict__ yb, const int* __restrict__ offs,
    const int* __restrict__ csr, const float* __restrict__ z,
    const int* __restrict__ starts, const float* __restrict__ wT,
    const float* __restrict__ cbf, const float* __restrict__ l1wf,
    const float* __restrict__ l1bf, const float* __restrict__ l2wf,
    const float* __restrict__ l2bf, float* __restrict__ outp)
{
    __shared__ u64  keys[256];
    __shared__ int  sel[KP];
    __shared__ float pT[64*32];          // pT[ch][rank], ranks 30,31 zeroed
    __shared__ float part[8*832];
    __shared__ float cbuf[832];
    __shared__ float fbuf[NH];
    __shared__ float logitsS[NCLS];
    int g = blockIdx.x, tid = threadIdx.x;
    int s = starts[g], e = starts[g+1];
    int cnt = e - s; if (cnt > 256) cnt = 256; if (cnt < 0) cnt = 0;

    // ---- phase A: key = h3[node][63] = relu(mean_csr(y[:,63]) + z[node][63]) ----
    u64 key = 0xFFFFFFFFFFFFFFFFull;
    if (tid < cnt){
        int node = s + tid;
        int o0 = offs[node], o1 = offs[node+1];
        float a = 0.f;
        int ee = o0;
        for (; ee + 3 < o1; ee += 4){
            float v0 = __uint_as_float((unsigned)yb[(size_t)csr[ee+0]*NH + 63] << 16);
            float v1 = __uint_as_float((unsigned)yb[(size_t)csr[ee+1]*NH + 63] << 16);
            float v2 = __uint_as_float((unsigned)yb[(size_t)csr[ee+2]*NH + 63] << 16);
            float v3 = __uint_as_float((unsigned)yb[(size_t)csr[ee+3]*NH + 63] << 16);
            a += v0; a += v1; a += v2; a += v3;       // same order as old gather
        }
        for (; ee < o1; ++ee)
            a += __uint_as_float((unsigned)yb[(size_t)csr[ee]*NH + 63] << 16);
        float dd = (float)(o1 - o0); dd = dd > 1.f ? dd : 1.f;
        float inv = 1.f / dd;
        float v = a*inv + z[(size_t)node*NH + 63];
        v = v > 0.f ? v : 0.f;
        unsigned u = __float_as_uint(v);
        unsigned m = (u & 0x80000000u) ? ~u : (u | 0x80000000u);
        unsigned d = ~m;                               // descending map
        key = ((u64)d << 32) | (unsigned)tid;
    }
    keys[tid] = key;
    __syncthreads();
    // bitonic sort, 256 elements, ascending
    for (int k = 2; k <= 256; k <<= 1){
        for (int j = k >> 1; j > 0; j >>= 1){
            int partner = tid ^ j;
            u64 a = keys[tid], b = keys[partner];
            bool up = ((tid & k) == 0);
            bool amin = a < b;
            u64 keep;
            if (partner > tid) keep = (up == amin) ? a : b;
            else               keep = (up == amin) ? b : a;
            __syncthreads();
            keys[tid] = keep;
            __syncthreads();
        }
    }
    if (tid < KP){
        u64 kk = keys[tid];
        sel[tid] = ((unsigned)(kk >> 32) == 0xFFFFFFFFu) ? -1 : (int)(kk & 0xFFFFFFFFu);
    }
    if (tid < 64){ pT[tid*32 + 30] = 0.f; pT[tid*32 + 31] = 0.f; }
    __syncthreads();

    // ---- phase B: full-row re-gather for the 30 winners -> pT (bitwise = old gather) ----
    #pragma unroll
    for (int r0 = 0; r0 < 32; r0 += 16){
        int r = r0 + (tid >> 4);
        int q = tid & 15;
        if (r < KP){
            float4 v = make_float4(0.f,0.f,0.f,0.f);
            int li = sel[r];
            if (li >= 0){
                int node = s + li;
                int o0 = offs[node], o1 = offs[node+1];
                float a0=0.f, a1=0.f, a2=0.f, a3=0.f;
                int ee = o0;
                for (; ee + 3 < o1; ee += 4){
                    int s0 = csr[ee], s1 = csr[ee+1], s2 = csr[ee+2], s3 = csr[ee+3];
                    uint2 u0 = *(const uint2*)&yb[(size_t)s0*NH + q*4];
                    uint2 u1 = *(const uint2*)&yb[(size_t)s1*NH + q*4];
                    uint2 u2 = *(const uint2*)&yb[(size_t)s2*NH + q*4];
                    uint2 u3 = *(const uint2*)&yb[(size_t)s3*NH + q*4];
                    acc4(u0, a0,a1,a2,a3); acc4(u1, a0,a1,a2,a3);
                    acc4(u2, a0,a1,a2,a3); acc4(u3, a0,a1,a2,a3);
                }
                for (; ee < o1; ++ee){
                    uint2 u = *(const uint2*)&yb[(size_t)csr[ee]*NH + q*4];
                    acc4(u, a0,a1,a2,a3);
                }
                float dd = (float)(o1 - o0); dd = dd > 1.f ? dd : 1.f;
                float inv = 1.f / dd;
                float4 zz = *(const float4*)&z[(size_t)node*NH + q*4];
                v.x = a0*inv + zz.x; v.y = a1*inv + zz.y;
                v.z = a2*inv + zz.z; v.w = a3*inv + zz.w;
                v.x = v.x > 0.f ? v.x : 0.f;  v.y = v.y > 0.f ? v.y : 0.f;
                v.z = v.z > 0.f ? v.z : 0.f;  v.w = v.w > 0.f ? v.w : 0.f;
            }
            pT[(q*4+0)*32 + r] = v.x;
            pT[(q*4+1)*32 + r] = v.y;
            pT[(q*4+2)*32 + r] = v.z;
            pT[(q*4+3)*32 + r] = v.w;
        }
    }
    __syncthreads();

    // ---- conv1d ----
    int o = tid & 31, chg = tid >> 5;
    float acc[26];
    #pragma unroll
    for (int t = 0; t < 26; ++t) acc[t] = 0.f;
    for (int c8 = 0; c8 < 8; ++c8){
        int ch = chg*8 + c8;
        const float4* prow = (const float4*)&pT[ch*32];
        float p[32];
        #pragma unroll
        for (int q = 0; q < 8; ++q){
            float4 v = prow[q];
            p[4*q]=v.x; p[4*q+1]=v.y; p[4*q+2]=v.z; p[4*q+3]=v.w;
        }
        const float* wrow = &wT[ch*160 + o];
        #pragma unroll
        for (int h = 0; h < 5; ++h){
            float wv = wrow[h*32];
            #pragma unroll
            for (int t = 0; t < 26; ++t) acc[t] += p[t+h]*wv;
        }
    }
    #pragma unroll
    for (int t = 0; t < 26; ++t) part[chg*832 + o*26 + t] = acc[t];
    __syncthreads();

    for (int i = tid; i < 832; i += 256){
        int oo = i / 26;
        float a = cbf[oo];
        #pragma unroll
        for (int cg = 0; cg < 8; ++cg) a += part[cg*832 + i];
        cbuf[i] = a > 0.f ? a : 0.f;
    }
    __syncthreads();

    {   // fc1: 832 -> 64
        int p = tid >> 6, j = tid & 63;
        float a = 0.f;
        int m0 = p*208;
        #pragma unroll 4
        for (int m = m0; m < m0 + 208; ++m)
            a += cbuf[m] * l1wf[(size_t)m*NH + j];
        part[p*NH + j] = a;
    }
    __syncthreads();
    if (tid < NH){
        float v = part[tid] + part[NH+tid] + part[2*NH+tid] + part[3*NH+tid] + l1bf[tid];
        fbuf[tid] = v > 0.f ? v : 0.f;
    }
    __syncthreads();
    if (tid < NCLS){
        float a = l2bf[tid];
        #pragma unroll
        for (int j = 0; j < NH; ++j) a += fbuf[j] * l2wf[j*NCLS + tid];
        logitsS[tid] = a;
    }
    __syncthreads();
    if (tid == 0){
        float m = logitsS[0];
        for (int c = 1; c < NCLS; ++c) m = fmaxf(m, logitsS[c]);
        float ssum = 0.f;
        for (int c = 0; c < NCLS; ++c) ssum += expf(logitsS[c]-m);
        float lse = m + logf(ssum);
        for (int c = 0; c < NCLS; ++c)
            outp[(size_t)g*NCLS + c] = logitsS[c] - lse;
    }
}

extern "C" void kernel_launch(void* const* d_in, const int* in_sizes, int n_in,
                              void* d_out, int out_size, void* d_ws, size_t ws_size,
                              hipStream_t stream) {
    const void* x    = d_in[0];
    const int*  ei   = (const int*)d_in[1];
    const int*  batch= (const int*)d_in[2];
    const void *W1l=d_in[3], *b1=d_in[4],  *W1r=d_in[5];
    const void *W2l=d_in[6], *b2=d_in[7],  *W2r=d_in[8];
    const void *W3l=d_in[9], *b3=d_in[10], *W3r=d_in[11];
    const void *convw=d_in[12], *convb=d_in[13];
    const void *l1w=d_in[14], *l1b=d_in[15];
    const void *l2w=d_in[16], *l2b=d_in[17];
    float* out = (float*)d_out;

    float* wsf = (float*)d_ws;
    ushort_t* yA = (ushort_t*)wsf;                        // NND*64 bf16
    float* zA  = wsf + (size_t)NND*NH/2;                  // NND*64 f32
    ushort_t* yB = (ushort_t*)(zA + (size_t)NND*NH);      // NND*64 bf16
    float* zB  = (float*)(yB + (size_t)NND*NH);           // NND*64 f32
    int2* bedges = (int2*)(zB + (size_t)NND*NH);          // NE int2
    ushort_t* wB1 = (ushort_t*)(bedges + NE);             // 16384
    ushort_t* wB2 = wB1 + 16384;                          // 8192
    ushort_t* wB3 = wB2 + 8192;                           // 8192
    float* b1f  = (float*)(wB3 + 8192);                   // 64
    float* b2f  = b1f + 64;
    float* b3f  = b2f + 64;
    float* wT   = b3f + 64;                               // 10240
    float* cbf  = wT + 10240;                             // 32
    float* l1wf = cbf + 32;                               // 53248
    float* l1bf = l1wf + 53248;                           // 64
    float* l2wf = l1bf + 64;                              // 640
    float* l2bf = l2wf + 640;                             // 10 (+pad)
    int* starts = (int*)(l2bf + 16);                      // 513
    int* bcnt   = starts + 520;                           // 49
    int* dctr   = bcnt + NBKT;                            // 1 (contiguous w/ bcnt)
    int* bbase  = bcnt + 64;                              // 50
    int* bcur   = bbase + 64;                             // 49
    int* offs   = bcur + 64;                              // 50001
    int* csr    = offs + NND + 3;                         // 800000

    // zero bcnt[49] + dctr (contiguous 50 ints)
    (void)hipMemsetAsync(bcnt, 0, 50*sizeof(int), stream);

    // K1: count(+scan fold) || setup
    k1_kernel<<<NTILE + NSET, 256, 0, stream>>>(
        (const unsigned*)x, ei, batch, starts,
        W1l, W1r, b1, W2l, W2r, b2, W3l, W3r, b3,
        convw, convb, l1w, l1b, l2w, l2b,
        wB1, wB2, wB3, b1f, b2f, b3f,
        wT, cbf, l1wf, l1bf, l2wf, l2bf,
        bcnt, dctr, bbase, bcur, offs);

    // K2: layer-1 GEMM || bucket_scatter
    k2_kernel<<<NG1 + NTILE, 256, 0, stream>>>(
        x, ei, wB1, b1f, yA, zA, bcur, bedges);

    // K3: per-bucket fine CSR
    csr_finalize<<<NBKT, 1024, 0, stream>>>(bedges, bbase, offs, csr);

    // K4/K5: fused gather+GEMM layers 2 and 3
    gather_mfma<<<NG1, 256, 0, stream>>>(yA, offs, csr, zA, wB2, b2f, yB, zB);
    gather_mfma<<<NG1, 256, 0, stream>>>(yB, offs, csr, zB, wB3, b3f, yA, zA);

    // K6: fused final-gather + sort-pool + conv + MLP + log_softmax
    head4_kernel<<<NB, 256, 0, stream>>>(yA, offs, csr, zA, starts,
                                         wT, cbf, l1wf, l1bf, l2wf, l2bf, out);
}

// Round 15
// 260.785 us; speedup vs baseline: 2.0679x; 1.0301x over previous
//
#include <hip/hip_runtime.h>
#include <hip/hip_bf16.h>
#include <math.h>

#define NND 50000
#define NE 800000
#define NF 128
#define NH 64
#define NB 512
#define KP 30
#define NCLS 10
#define NBKT 49              // coarse buckets of 1024 dsts
#define NTILE 196            // edge tiles of 4096
#define NG1 782              // layer GEMM blocks (64 nodes each)
#define NSET 208             // setup blocks (208*256 = 53248)

typedef __hip_bfloat16 bf16;
typedef unsigned long long u64;
typedef unsigned short ushort_t;
typedef __attribute__((ext_vector_type(8))) short bf16x8;   // 8 bf16 (4 VGPRs)
typedef __attribute__((ext_vector_type(4))) float f32x4;

__device__ __forceinline__ float ldF(const void* p, size_t i, int isbf){
    return isbf ? __bfloat162float(((const bf16*)p)[i]) : ((const float*)p)[i];
}

// fp32 -> bf16 bits, round-to-nearest-even (matches HW/numpy)
__device__ __forceinline__ ushort_t f2bf(float v){
    unsigned u = __float_as_uint(v);
    unsigned r = u + 0x7FFFu + ((u >> 16) & 1u);
    return (ushort_t)(r >> 16);
}

// ---- wave-uniform dtype detection (no LDS, no barriers; all lanes must be active) ----
__device__ __forceinline__ int floatsAreBf16(const unsigned* __restrict__ xw, int tid){
    unsigned w = xw[tid & 63];
    int ex = (int)((w >> 7) & 0xFF);
    u64 m = __ballot(ex >= 100 && ex <= 140);   // low-half bf16 exponent sanity
    return __popcll(m) >= 32;
}
__device__ __forceinline__ int intsAreI64(const int* __restrict__ ew, int tid){
    u64 m = __ballot(ew[2*(tid & 63) + 1] == 0); // LE int64 -> odd words zero
    return __popcll(m) >= 48;
}

__device__ __forceinline__ int edgeSrc(const int* ei, int e, int i64){
    return i64 ? ei[2*e] : ei[e];
}
__device__ __forceinline__ int edgeDst(const int* ei, int e, int i64){
    return i64 ? ei[2*NE + 2*e] : ei[NE + e];
}

// ========== K1: bucket_count(+last-block scan fold) || setup ==========
__global__ __launch_bounds__(256) void k1_kernel(
    const unsigned* __restrict__ xw, const int* __restrict__ ei,
    const int* __restrict__ batch, int* __restrict__ starts,
    const void* W1l, const void* W1r, const void* b1,
    const void* W2l, const void* W2r, const void* b2,
    const void* W3l, const void* W3r, const void* b3,
    const void* convw, const void* convb,
    const void* l1w, const void* l1b, const void* l2w, const void* l2b,
    ushort_t* __restrict__ wB1, ushort_t* __restrict__ wB2, ushort_t* __restrict__ wB3,
    float* __restrict__ b1f, float* __restrict__ b2f, float* __restrict__ b3f,
    float* __restrict__ wT, float* __restrict__ cbf,
    float* __restrict__ l1wf, float* __restrict__ l1bf,
    float* __restrict__ l2wf, float* __restrict__ l2bf,
    int* __restrict__ bcnt, int* __restrict__ dctr,
    int* __restrict__ bbase, int* __restrict__ bcur, int* __restrict__ offs)
{
    int tid = threadIdx.x;
    if (blockIdx.x < NTILE){
        // ---- bucket count ----
        __shared__ int lh[NBKT];
        __shared__ int sc[NBKT];
        __shared__ int lastFlag;
        int i64 = intsAreI64(ei, tid);
        if (tid < NBKT) lh[tid] = 0;
        __syncthreads();
        int t0 = blockIdx.x*4096;
        #pragma unroll 4
        for (int k = 0; k < 16; ++k){
            int e = t0 + k*256 + tid;
            if (e < NE) atomicAdd(&lh[edgeDst(ei,e,i64) >> 10], 1);
        }
        __syncthreads();
        if (tid < NBKT && lh[tid]) atomicAdd(&bcnt[tid], lh[tid]);
        __syncthreads();
        if (tid == 0){
            __threadfence();
            int old = atomicAdd(dctr, 1);
            lastFlag = (old == NTILE-1) ? 1 : 0;
        }
        __syncthreads();
        if (lastFlag){
            if (tid < NBKT) sc[tid] = atomicAdd(&bcnt[tid], 0);   // atomic read
            __syncthreads();
            if (tid == 0){
                int acc = 0;
                for (int b = 0; b < NBKT; ++b){
                    bbase[b] = acc; bcur[b] = acc; acc += sc[b];
                }
                bbase[NBKT] = acc;
                offs[NND] = NE;
            }
        }
    } else {
        // ---- setup: starts + weight preconvert + MFMA B-frag swizzle ----
        int wbf = floatsAreBf16(xw, tid);
        int i64 = intsAreI64(ei, tid);
        int i = (blockIdx.x - NTILE)*256 + tid;
        if (i < NND){
            int b  = i64 ? batch[2*i] : batch[i];
            int pb = (i == 0) ? -1 : (i64 ? batch[2*(i-1)] : batch[i-1]);
            for (int g = pb+1; g <= b; ++g) starts[g] = i;
            if (i == NND-1) for (int g = b+1; g <= NB; ++g) starts[g] = NND;
        }
        // B-frag swizzle: [c][t][lane][j]; k=c*32+(lane>>4)*8+j, n=t*16+(lane&15)
        {
            int j = i & 7, lane = (i >> 3) & 63, t = (i >> 9) & 7, c = i >> 12;
            int k = c*32 + (lane >> 4)*8 + j;
            int n = t*16 + (lane & 15);
            if (i < 16384){
                float v = (n < 64) ? ldF(W1l, (size_t)k*NH + n, wbf)
                                   : ldF(W1r, (size_t)k*NH + (n-64), wbf);
                wB1[i] = f2bf(v);
            }
            if (i < 8192){
                float v2 = (n < 64) ? ldF(W2l, (size_t)k*NH + n, wbf)
                                    : ldF(W2r, (size_t)k*NH + (n-64), wbf);
                float v3 = (n < 64) ? ldF(W3l, (size_t)k*NH + n, wbf)
                                    : ldF(W3r, (size_t)k*NH + (n-64), wbf);
                wB2[i] = f2bf(v2);
                wB3[i] = f2bf(v3);
            }
        }
        if (i < 64){
            b1f[i] = ldF(b1, i, wbf);
            b2f[i] = ldF(b2, i, wbf);
            b3f[i] = ldF(b3, i, wbf);
            l1bf[i] = ldF(l1b, i, wbf);
        }
        if (i < 10240){
            int o = i / 320, rem = i - o*320, ch = rem/5, h = rem - ch*5;
            wT[ch*160 + h*32 + o] = ldF(convw, i, wbf);   // wT[ch][h][o]
        }
        if (i < 53248) l1wf[i] = ldF(l1w, i, wbf);
        if (i < 640)   l2wf[i] = ldF(l2w, i, wbf);
        if (i < 32)    cbf[i]  = ldF(convb, i, wbf);
        if (i < 10)    l2bf[i] = ldF(l2b, i, wbf);
    }
}

// ========== K2: layer-1 MFMA GEMM || bucket_scatter (independent) ==========
__global__ __launch_bounds__(256) void k2_kernel(
    const void* __restrict__ x, const int* __restrict__ ei,
    const ushort_t* __restrict__ wB1, const float* __restrict__ b1f,
    ushort_t* __restrict__ ybf, float* __restrict__ z,
    int* __restrict__ bcur, int2* __restrict__ bedges)
{
    int tid = threadIdx.x;
    if (blockIdx.x < NG1){
        // ---- L1 GEMM: [y|z] = x @ [W1l|W1r] + [0|b1], K=128 ----
        constexpr int K = NF, KC = K/32, RS = K + 8;
        __shared__ ushort_t hA[64*RS];
        int isbf = floatsAreBf16((const unsigned*)x, tid);
        int base = blockIdx.x * 64;
        for (int i = tid; i < 64*K; i += 256){
            int r = i / K, c = i - r*K;
            int node = base + r;
            float v = (node < NND) ? ldF(x, (size_t)node*K + c, isbf) : 0.f;
            hA[r*RS + c] = f2bf(v);
        }
        __syncthreads();
        int lane = tid & 63, w = tid >> 6;
        int n16 = lane & 15, quad = lane >> 4;
        f32x4 acc[8];
        #pragma unroll
        for (int t = 0; t < 8; ++t) acc[t] = (f32x4){0.f,0.f,0.f,0.f};
        const bf16x8* bp = (const bf16x8*)wB1;
        #pragma unroll
        for (int c = 0; c < KC; ++c){
            bf16x8 a = *(const bf16x8*)&hA[(w*16 + n16)*RS + c*32 + quad*8];
            #pragma unroll
            for (int t = 0; t < 8; ++t){
                bf16x8 b = bp[(c*8 + t)*64 + lane];
                acc[t] = __builtin_amdgcn_mfma_f32_16x16x32_bf16(a, b, acc[t], 0, 0, 0);
            }
        }
        #pragma unroll
        for (int t = 0; t < 8; ++t){
            int f = (t & 3)*16 + n16;
            float bv = (t >= 4) ? b1f[f] : 0.f;
            #pragma unroll
            for (int r = 0; r < 4; ++r){
                int node = base + w*16 + quad*4 + r;
                if (node < NND){
                    if (t < 4) ybf[(size_t)node*NH + f] = f2bf(acc[t][r]);
                    else       z[(size_t)node*NH + f] = acc[t][r] + bv;
                }
            }
        }
    } else {
        // ---- bucket scatter ----
        __shared__ int lh[NBKT];
        __shared__ int lcur[NBKT];
        int i64 = intsAreI64(ei, tid);
        if (tid < NBKT) lh[tid] = 0;
        __syncthreads();
        int t0 = (blockIdx.x - NG1)*4096;
        int myd[16], mys[16];
        int cnt = 0;
        #pragma unroll 4
        for (int k = 0; k < 16; ++k){
            int e = t0 + k*256 + tid;
            if (e < NE){
                int d = edgeDst(ei,e,i64), s_ = edgeSrc(ei,e,i64);
                myd[cnt] = d; mys[cnt] = s_; ++cnt;
                atomicAdd(&lh[d >> 10], 1);
            }
        }
        __syncthreads();
        if (tid < NBKT) lcur[tid] = lh[tid] ? atomicAdd(&bcur[tid], lh[tid]) : 0;
        __syncthreads();
        for (int k = 0; k < cnt; ++k){
            int b = myd[k] >> 10;
            int p = atomicAdd(&lcur[b], 1);
            bedges[p] = make_int2(mys[k], myd[k]);
        }
    }
}

__global__ __launch_bounds__(1024) void csr_finalize(const int2* __restrict__ bedges,
                                                     const int* __restrict__ bbase,
                                                     int* __restrict__ offs,
                                                     int* __restrict__ csr){
    __shared__ int hist[1024];
    int b = blockIdx.x;
    int tid = threadIdx.x;
    int dst0 = b << 10;
    int nd = NND - dst0; if (nd > 1024) nd = 1024;
    int e0 = bbase[b], e1 = bbase[b+1];
    hist[tid] = 0;
    __syncthreads();
    for (int e = e0 + tid; e < e1; e += 1024)
        atomicAdd(&hist[bedges[e].y - dst0], 1);
    __syncthreads();
    int own = hist[tid];
    for (int st = 1; st < 1024; st <<= 1){
        int v = (tid >= st) ? hist[tid-st] : 0;
        __syncthreads();
        hist[tid] += v;
        __syncthreads();
    }
    int excl = hist[tid] - own;
    if (tid < nd) offs[dst0 + tid] = e0 + excl;
    __syncthreads();
    hist[tid] = excl;
    __syncthreads();
    for (int e = e0 + tid; e < e1; e += 1024){
        int2 ed = bedges[e];
        int p = atomicAdd(&hist[ed.y - dst0], 1);
        csr[e0 + p] = ed.x;
    }
}

__device__ __forceinline__ void addbf8(uint4 u, float* a){
    a[0] += __uint_as_float(u.x << 16);
    a[1] += __uint_as_float(u.x & 0xFFFF0000u);
    a[2] += __uint_as_float(u.y << 16);
    a[3] += __uint_as_float(u.y & 0xFFFF0000u);
    a[4] += __uint_as_float(u.z << 16);
    a[5] += __uint_as_float(u.z & 0xFFFF0000u);
    a[6] += __uint_as_float(u.w << 16);
    a[7] += __uint_as_float(u.w & 0xFFFF0000u);
}

// ------ FUSED: h = relu(mean_csr(y)+z) -> LDS A-tile -> MFMA [y'|z'] (layers 2,3) ----
// ykey_out (nullable): compact copy of y'[:,63] for the head's sort-key gather.
__global__ __launch_bounds__(256) void gather_mfma(
    const ushort_t* __restrict__ yb, const int* __restrict__ offs,
    const int* __restrict__ csr, const float* __restrict__ z,
    const ushort_t* __restrict__ wB, const float* __restrict__ bfp,
    ushort_t* __restrict__ ybf_out, float* __restrict__ z_out,
    ushort_t* __restrict__ ykey_out)
{
    constexpr int K = NH;
    constexpr int KC = K/32;
    constexpr int RS = K + 8;
    __shared__ ushort_t hA[64*RS];
    int tid = threadIdx.x;
    int base = blockIdx.x * 64;

    {   // phase A: gather+finalize 64 nodes into hA
        int nl = tid >> 2, q = tid & 3;
        int node = base + nl;
        float acc[16];
        #pragma unroll
        for (int i = 0; i < 16; ++i) acc[i] = 0.f;
        ushort_t row[16];
        if (node < NND){
            int o0 = offs[node], o1 = offs[node+1];
            int e = o0;
            for (; e + 3 < o1; e += 4){
                int s0 = csr[e], s1 = csr[e+1], s2 = csr[e+2], s3 = csr[e+3];
                const uint4* p0 = (const uint4*)&yb[(size_t)s0*NH + q*16];
                const uint4* p1 = (const uint4*)&yb[(size_t)s1*NH + q*16];
                const uint4* p2 = (const uint4*)&yb[(size_t)s2*NH + q*16];
                const uint4* p3 = (const uint4*)&yb[(size_t)s3*NH + q*16];
                uint4 a0 = p0[0], a1 = p0[1], b0 = p1[0], b1 = p1[1];
                uint4 c0 = p2[0], c1 = p2[1], d0 = p3[0], d1 = p3[1];
                addbf8(a0, acc); addbf8(a1, acc+8);
                addbf8(b0, acc); addbf8(b1, acc+8);
                addbf8(c0, acc); addbf8(c1, acc+8);
                addbf8(d0, acc); addbf8(d1, acc+8);
            }
            for (; e < o1; ++e){
                const uint4* p0 = (const uint4*)&yb[(size_t)csr[e]*NH + q*16];
                uint4 a0 = p0[0], a1 = p0[1];
                addbf8(a0, acc); addbf8(a1, acc+8);
            }
            float dd = (float)(o1 - o0); dd = dd > 1.f ? dd : 1.f;
            float inv = 1.f / dd;
            const float4* zp = (const float4*)&z[(size_t)node*NH + q*16];
            #pragma unroll
            for (int i4 = 0; i4 < 4; ++i4){
                float4 zz = zp[i4];
                float v0 = acc[i4*4+0]*inv + zz.x;
                float v1 = acc[i4*4+1]*inv + zz.y;
                float v2 = acc[i4*4+2]*inv + zz.z;
                float v3 = acc[i4*4+3]*inv + zz.w;
                row[i4*4+0] = f2bf(v0 > 0.f ? v0 : 0.f);
                row[i4*4+1] = f2bf(v1 > 0.f ? v1 : 0.f);
                row[i4*4+2] = f2bf(v2 > 0.f ? v2 : 0.f);
                row[i4*4+3] = f2bf(v3 > 0.f ? v3 : 0.f);
            }
        } else {
            #pragma unroll
            for (int i = 0; i < 16; ++i) row[i] = 0;
        }
        unsigned pk[8];
        #pragma unroll
        for (int i = 0; i < 8; ++i)
            pk[i] = (unsigned)row[2*i] | ((unsigned)row[2*i+1] << 16);
        *(uint4*)&hA[nl*RS + q*16]     = make_uint4(pk[0],pk[1],pk[2],pk[3]);
        *(uint4*)&hA[nl*RS + q*16 + 8] = make_uint4(pk[4],pk[5],pk[6],pk[7]);
    }
    __syncthreads();

    int lane = tid & 63, w = tid >> 6;
    int n16 = lane & 15, quad = lane >> 4;
    f32x4 acc[8];
    #pragma unroll
    for (int t = 0; t < 8; ++t) acc[t] = (f32x4){0.f,0.f,0.f,0.f};
    const bf16x8* bp = (const bf16x8*)wB;
    #pragma unroll
    for (int c = 0; c < KC; ++c){
        bf16x8 a = *(const bf16x8*)&hA[(w*16 + n16)*RS + c*32 + quad*8];
        #pragma unroll
        for (int t = 0; t < 8; ++t){
            bf16x8 b = bp[(c*8 + t)*64 + lane];
            acc[t] = __builtin_amdgcn_mfma_f32_16x16x32_bf16(a, b, acc[t], 0, 0, 0);
        }
    }
    #pragma unroll
    for (int t = 0; t < 8; ++t){
        int f = (t & 3)*16 + n16;
        float bv = (t >= 4) ? bfp[f] : 0.f;
        #pragma unroll
        for (int r = 0; r < 4; ++r){
            int node = base + w*16 + quad*4 + r;
            if (node < NND){
                if (t < 4){
                    ushort_t yv = f2bf(acc[t][r]);
                    ybf_out[(size_t)node*NH + f] = yv;
                    if (ykey_out != nullptr && t == 3 && n16 == 15)
                        ykey_out[node] = yv;          // compact y'[:,63] for sort keys
                } else {
                    z_out[(size_t)node*NH + f] = acc[t][r] + bv;
                }
            }
        }
    }
}

__device__ __forceinline__ void acc4(uint2 u, float& a0, float& a1, float& a2, float& a3){
    a0 += __uint_as_float(u.x << 16);
    a1 += __uint_as_float(u.x & 0xFFFF0000u);
    a2 += __uint_as_float(u.y << 16);
    a3 += __uint_as_float(u.y & 0xFFFF0000u);
}

// ====== head v4: compact-key gather + bitonic top-30 + winner-row re-gather +
//        conv + fc1 + fc2 + log_softmax ======
__global__ __launch_bounds__(256) void head4_kernel(
    const ushort_t* __restrict__ yb, const ushort_t* __restrict__ ykey,
    const int* __restrict__ offs, const int* __restrict__ csr,
    const float* __restrict__ z, const int* __restrict__ starts,
    const float* __restrict__ wT, const float* __restrict__ cbf,
    const float* __restrict__ l1wf, const float* __restrict__ l1bf,
    const float* __restrict__ l2wf, const float* __restrict__ l2bf,
    float* __restrict__ outp)
{
    __shared__ u64  keys[256];
    __shared__ int  sel[KP];
    __shared__ float pT[64*32];          // pT[ch][rank], ranks 30,31 zeroed
    __shared__ float part[8*832];
    __shared__ float cbuf[832];
    __shared__ float fbuf[NH];
    __shared__ float logitsS[NCLS];
    int g = blockIdx.x, tid = threadIdx.x;
    int s = starts[g], e = starts[g+1];
    int cnt = e - s; if (cnt > 256) cnt = 256; if (cnt < 0) cnt = 0;

    // ---- phase A: key from compact ykey (L2-resident 100KB; same order as gather) ----
    u64 key = 0xFFFFFFFFFFFFFFFFull;
    if (tid < cnt){
        int node = s + tid;
        int o0 = offs[node], o1 = offs[node+1];
        float a = 0.f;
        int ee = o0;
        for (; ee + 3 < o1; ee += 4){
            float v0 = __uint_as_float((unsigned)ykey[csr[ee+0]] << 16);
            float v1 = __uint_as_float((unsigned)ykey[csr[ee+1]] << 16);
            float v2 = __uint_as_float((unsigned)ykey[csr[ee+2]] << 16);
            float v3 = __uint_as_float((unsigned)ykey[csr[ee+3]] << 16);
            a += v0; a += v1; a += v2; a += v3;       // same order as full gather
        }
        for (; ee < o1; ++ee)
            a += __uint_as_float((unsigned)ykey[csr[ee]] << 16);
        float dd = (float)(o1 - o0); dd = dd > 1.f ? dd : 1.f;
        float inv = 1.f / dd;
        float v = a*inv + z[(size_t)node*NH + 63];
        v = v > 0.f ? v : 0.f;
        unsigned u = __float_as_uint(v);
        unsigned m = (u & 0x80000000u) ? ~u : (u | 0x80000000u);
        unsigned d = ~m;                               // descending map
        key = ((u64)d << 32) | (unsigned)tid;
    }
    keys[tid] = key;
    __syncthreads();
    // bitonic sort, 256 elements, ascending
    for (int k = 2; k <= 256; k <<= 1){
        for (int j = k >> 1; j > 0; j >>= 1){
            int partner = tid ^ j;
            u64 a = keys[tid], b = keys[partner];
            bool up = ((tid & k) == 0);
            bool amin = a < b;
            u64 keep;
            if (partner > tid) keep = (up == amin) ? a : b;
            else               keep = (up == amin) ? b : a;
            __syncthreads();
            keys[tid] = keep;
            __syncthreads();
        }
    }
    if (tid < KP){
        u64 kk = keys[tid];
        sel[tid] = ((unsigned)(kk >> 32) == 0xFFFFFFFFu) ? -1 : (int)(kk & 0xFFFFFFFFu);
    }
    if (tid < 64){ pT[tid*32 + 30] = 0.f; pT[tid*32 + 31] = 0.f; }
    __syncthreads();

    // ---- phase B: full-row re-gather for the 30 winners -> pT (bitwise = old gather) ----
    #pragma unroll
    for (int r0 = 0; r0 < 32; r0 += 16){
        int r = r0 + (tid >> 4);
        int q = tid & 15;
        if (r < KP){
            float4 v = make_float4(0.f,0.f,0.f,0.f);
            int li = sel[r];
            if (li >= 0){
                int node = s + li;
                int o0 = offs[node], o1 = offs[node+1];
                float a0=0.f, a1=0.f, a2=0.f, a3=0.f;
                int ee = o0;
                for (; ee + 3 < o1; ee += 4){
                    int s0 = csr[ee], s1 = csr[ee+1], s2 = csr[ee+2], s3 = csr[ee+3];
                    uint2 u0 = *(const uint2*)&yb[(size_t)s0*NH + q*4];
                    uint2 u1 = *(const uint2*)&yb[(size_t)s1*NH + q*4];
                    uint2 u2 = *(const uint2*)&yb[(size_t)s2*NH + q*4];
                    uint2 u3 = *(const uint2*)&yb[(size_t)s3*NH + q*4];
                    acc4(u0, a0,a1,a2,a3); acc4(u1, a0,a1,a2,a3);
                    acc4(u2, a0,a1,a2,a3); acc4(u3, a0,a1,a2,a3);
                }
                for (; ee < o1; ++ee){
                    uint2 u = *(const uint2*)&yb[(size_t)csr[ee]*NH + q*4];
                    acc4(u, a0,a1,a2,a3);
                }
                float dd = (float)(o1 - o0); dd = dd > 1.f ? dd : 1.f;
                float inv = 1.f / dd;
                float4 zz = *(const float4*)&z[(size_t)node*NH + q*4];
                v.x = a0*inv + zz.x; v.y = a1*inv + zz.y;
                v.z = a2*inv + zz.z; v.w = a3*inv + zz.w;
                v.x = v.x > 0.f ? v.x : 0.f;  v.y = v.y > 0.f ? v.y : 0.f;
                v.z = v.z > 0.f ? v.z : 0.f;  v.w = v.w > 0.f ? v.w : 0.f;
            }
            pT[(q*4+0)*32 + r] = v.x;
            pT[(q*4+1)*32 + r] = v.y;
            pT[(q*4+2)*32 + r] = v.z;
            pT[(q*4+3)*32 + r] = v.w;
        }
    }
    __syncthreads();

    // ---- conv1d ----
    int o = tid & 31, chg = tid >> 5;
    float acc[26];
    #pragma unroll
    for (int t = 0; t < 26; ++t) acc[t] = 0.f;
    for (int c8 = 0; c8 < 8; ++c8){
        int ch = chg*8 + c8;
        const float4* prow = (const float4*)&pT[ch*32];
        float p[32];
        #pragma unroll
        for (int q = 0; q < 8; ++q){
            float4 v = prow[q];
            p[4*q]=v.x; p[4*q+1]=v.y; p[4*q+2]=v.z; p[4*q+3]=v.w;
        }
        const float* wrow = &wT[ch*160 + o];
        #pragma unroll
        for (int h = 0; h < 5; ++h){
            float wv = wrow[h*32];
            #pragma unroll
            for (int t = 0; t < 26; ++t) acc[t] += p[t+h]*wv;
        }
    }
    #pragma unroll
    for (int t = 0; t < 26; ++t) part[chg*832 + o*26 + t] = acc[t];
    __syncthreads();

    for (int i = tid; i < 832; i += 256){
        int oo = i / 26;
        float a = cbf[oo];
        #pragma unroll
        for (int cg = 0; cg < 8; ++cg) a += part[cg*832 + i];
        cbuf[i] = a > 0.f ? a : 0.f;
    }
    __syncthreads();

    {   // fc1: 832 -> 64
        int p = tid >> 6, j = tid & 63;
        float a = 0.f;
        int m0 = p*208;
        #pragma unroll 4
        for (int m = m0; m < m0 + 208; ++m)
            a += cbuf[m] * l1wf[(size_t)m*NH + j];
        part[p*NH + j] = a;
    }
    __syncthreads();
    if (tid < NH){
        float v = part[tid] + part[NH+tid] + part[2*NH+tid] + part[3*NH+tid] + l1bf[tid];
        fbuf[tid] = v > 0.f ? v : 0.f;
    }
    __syncthreads();
    if (tid < NCLS){
        float a = l2bf[tid];
        #pragma unroll
        for (int j = 0; j < NH; ++j) a += fbuf[j] * l2wf[j*NCLS + tid];
        logitsS[tid] = a;
    }
    __syncthreads();
    if (tid == 0){
        float m = logitsS[0];
        for (int c = 1; c < NCLS; ++c) m = fmaxf(m, logitsS[c]);
        float ssum = 0.f;
        for (int c = 0; c < NCLS; ++c) ssum += expf(logitsS[c]-m);
        float lse = m + logf(ssum);
        for (int c = 0; c < NCLS; ++c)
            outp[(size_t)g*NCLS + c] = logitsS[c] - lse;
    }
}

extern "C" void kernel_launch(void* const* d_in, const int* in_sizes, int n_in,
                              void* d_out, int out_size, void* d_ws, size_t ws_size,
                              hipStream_t stream) {
    const void* x    = d_in[0];
    const int*  ei   = (const int*)d_in[1];
    const int*  batch= (const int*)d_in[2];
    const void *W1l=d_in[3], *b1=d_in[4],  *W1r=d_in[5];
    const void *W2l=d_in[6], *b2=d_in[7],  *W2r=d_in[8];
    const void *W3l=d_in[9], *b3=d_in[10], *W3r=d_in[11];
    const void *convw=d_in[12], *convb=d_in[13];
    const void *l1w=d_in[14], *l1b=d_in[15];
    const void *l2w=d_in[16], *l2b=d_in[17];
    float* out = (float*)d_out;

    float* wsf = (float*)d_ws;
    ushort_t* yA = (ushort_t*)wsf;                        // NND*64 bf16
    float* zA  = wsf + (size_t)NND*NH/2;                  // NND*64 f32
    ushort_t* yB = (ushort_t*)(zA + (size_t)NND*NH);      // NND*64 bf16
    float* zB  = (float*)(yB + (size_t)NND*NH);           // NND*64 f32
    int2* bedges = (int2*)(zB + (size_t)NND*NH);          // NE int2
    ushort_t* wB1 = (ushort_t*)(bedges + NE);             // 16384
    ushort_t* wB2 = wB1 + 16384;                          // 8192
    ushort_t* wB3 = wB2 + 8192;                           // 8192
    ushort_t* ykey = wB3 + 8192;                          // NND (compact y3[:,63])
    float* b1f  = (float*)(ykey + NND + 8);               // 64
    float* b2f  = b1f + 64;
    float* b3f  = b2f + 64;
    float* wT   = b3f + 64;                               // 10240
    float* cbf  = wT + 10240;                             // 32
    float* l1wf = cbf + 32;                               // 53248
    float* l1bf = l1wf + 53248;                           // 64
    float* l2wf = l1bf + 64;                              // 640
    float* l2bf = l2wf + 640;                             // 10 (+pad)
    int* starts = (int*)(l2bf + 16);                      // 513
    int* bcnt   = starts + 520;                           // 49
    int* dctr   = bcnt + NBKT;                            // 1 (contiguous w/ bcnt)
    int* bbase  = bcnt + 64;                              // 50
    int* bcur   = bbase + 64;                             // 49
    int* offs   = bcur + 64;                              // 50001
    int* csr    = offs + NND + 3;                         // 800000

    // zero bcnt[49] + dctr (contiguous 50 ints)
    (void)hipMemsetAsync(bcnt, 0, 50*sizeof(int), stream);

    // K1: count(+scan fold) || setup
    k1_kernel<<<NTILE + NSET, 256, 0, stream>>>(
        (const unsigned*)x, ei, batch, starts,
        W1l, W1r, b1, W2l, W2r, b2, W3l, W3r, b3,
        convw, convb, l1w, l1b, l2w, l2b,
        wB1, wB2, wB3, b1f, b2f, b3f,
        wT, cbf, l1wf, l1bf, l2wf, l2bf,
        bcnt, dctr, bbase, bcur, offs);

    // K2: layer-1 GEMM || bucket_scatter
    k2_kernel<<<NG1 + NTILE, 256, 0, stream>>>(
        x, ei, wB1, b1f, yA, zA, bcur, bedges);

    // K3: per-bucket fine CSR
    csr_finalize<<<NBKT, 1024, 0, stream>>>(bedges, bbase, offs, csr);

    // K4/K5: fused gather+GEMM layers 2 and 3 (K5 also emits compact ykey)
    gather_mfma<<<NG1, 256, 0, stream>>>(yA, offs, csr, zA, wB2, b2f, yB, zB, nullptr);
    gather_mfma<<<NG1, 256, 0, stream>>>(yB, offs, csr, zB, wB3, b3f, yA, zA, ykey);

    // K6: fused final-gather + sort-pool + conv + MLP + log_softmax
    head4_kernel<<<NB, 256, 0, stream>>>(yA, ykey, offs, csr, zA, starts,
                                         wT, cbf, l1wf, l1bf, l2wf, l2bf, out);
}